// Round 2
// baseline (679.595 us; speedup 1.0000x reference)
//
#include <hip/hip_runtime.h>
#include <cstddef>

#define NB 32
#define NF 64
#define NL 8192
#define NP 96
#define NH 8
#define SPLIT 16

// ws layout in floats:
#define WS_MEAN 0           // 2048
#define WS_STD  2048        // 2048
#define WS_RSTD 4096        // 2048
#define WS_KV   6144        // NB*NH*64 = 16384
#define WS_Z    22528       // NB*NH*8  = 2048
#define WS_OUT2 24576       // NB*NP*NF = 196608
#define WS_QPHI 221184      // NB*NF*NL = 16777216
#define WS_YT   16998400    // NB*NF*NL = 16777216   (total ~135 MB)

// ---------------- K1: RevIN stats per (b,f) ----------------
__global__ __launch_bounds__(256) void k_stats(const float* __restrict__ x,
                                               float* __restrict__ wmean,
                                               float* __restrict__ wstd,
                                               float* __restrict__ wrstd) {
  int bf = blockIdx.x;
  int tid = threadIdx.x;
  const float4* row4 = (const float4*)(x + (size_t)bf * NL);
  float s1 = 0.f, s2 = 0.f;
#pragma unroll
  for (int i = 0; i < NL / 4 / 256; i++) {
    float4 v = row4[tid + i * 256];
    s1 += v.x + v.y + v.z + v.w;
    s2 += v.x * v.x + v.y * v.y + v.z * v.z + v.w * v.w;
  }
  __shared__ float r1[256], r2[256];
  r1[tid] = s1; r2[tid] = s2;
  __syncthreads();
  for (int off = 128; off > 0; off >>= 1) {
    if (tid < off) { r1[tid] += r1[tid + off]; r2[tid] += r2[tid + off]; }
    __syncthreads();
  }
  if (tid == 0) {
    float m = r1[0] * (1.f / NL);
    float var = (r2[0] - (float)NL * m * m) * (1.f / (NL - 1));
    float sd = sqrtf(fmaxf(var, 0.f)) + 1e-5f;   // eps added to std (torch RevIN)
    wmean[bf] = m;
    wstd[bf] = sd;
    wrstd[bf] = 1.f / sd;
  }
}

// ---------------- K2: Q/K/V projections; phi(Q)->ws; KV,Z accumulation ----------------
__global__ __launch_bounds__(256) void k_kvq(
    const float* __restrict__ x,
    const float* __restrict__ gamma, const float* __restrict__ beta,
    const float* __restrict__ lnw, const float* __restrict__ lnb,
    const float* __restrict__ Wq, const float* __restrict__ bq,
    const float* __restrict__ Wk, const float* __restrict__ bk,
    const float* __restrict__ Wv, const float* __restrict__ bv,
    const float* __restrict__ wmean, const float* __restrict__ wrstd,
    float* __restrict__ qphi, float* __restrict__ wKV, float* __restrict__ wZ) {
  int tid = threadIdx.x;
  int b = blockIdx.x >> 5;                 // 32 tiles of 256 l per b
  int l = ((blockIdx.x & 31) << 8) + tid;

  // RevIN + LayerNorm, h in registers (single 64-float array; W/stat reads wave-uniform)
  float h[NF];
  float mu = 0.f;
#pragma unroll
  for (int f = 0; f < NF; f++) {
    float v = x[((size_t)(b * NF + f)) * NL + l];
    v = (v - wmean[b * NF + f]) * wrstd[b * NF + f] * gamma[f] + beta[f];
    h[f] = v;
    mu += v;
  }
  mu *= (1.f / NF);
  float var = 0.f;
#pragma unroll
  for (int f = 0; f < NF; f++) { float d = h[f] - mu; var += d * d; }
  float rs = rsqrtf(var * (1.f / NF) + 1e-5f);
#pragma unroll
  for (int f = 0; f < NF; f++) h[f] = (h[f] - mu) * rs * lnw[f] + lnb[f];

  __shared__ float kbuf[8][257], vbuf[8][257];   // [j][l] transposed: conflict-free writes
  __shared__ float red[256];
  __shared__ float zred[32];

  int chunk = tid >> 6;          // 0..3
  int dd = (tid & 63) >> 3;      // 0..7
  int ee = tid & 7;              // 0..7

  for (int hh = 0; hh < NH; hh++) {
    float q8[8], k8[8], v8[8];
#pragma unroll
    for (int j = 0; j < 8; j++) {
      q8[j] = bq[hh * 8 + j]; k8[j] = bk[hh * 8 + j]; v8[j] = bv[hh * 8 + j];
    }
#pragma unroll
    for (int f = 0; f < NF; f++) {
      float hf = h[f];
#pragma unroll
      for (int j = 0; j < 8; j++) {
        q8[j] = fmaf(hf, Wq[(hh * 8 + j) * NF + f], q8[j]);
        k8[j] = fmaf(hf, Wk[(hh * 8 + j) * NF + f], k8[j]);
        v8[j] = fmaf(hf, Wv[(hh * 8 + j) * NF + f], v8[j]);
      }
    }
#pragma unroll
    for (int j = 0; j < 8; j++) {
      float qq = q8[j];
      qphi[((size_t)(b * NF + hh * 8 + j)) * NL + l] = (qq > 0.f) ? (qq + 1.f) : __expf(qq);
      float kk = k8[j];
      kbuf[j][tid] = (kk > 0.f) ? (kk + 1.f) : __expf(kk);  // phi = elu+1
      vbuf[j][tid] = v8[j];
    }
    __syncthreads();
    // KV[d][e] partial over this block's 256 l values, 4 chunks x 64 (d,e) pairs
    float s = 0.f;
    int t0 = chunk * 64;
#pragma unroll 8
    for (int t = 0; t < 64; t++)
      s = fmaf(kbuf[dd][t0 + t], vbuf[ee][t0 + t], s);
    red[tid] = s;
    if (tid < 32) {
      int c2 = tid >> 3, d2 = tid & 7;
      float zs = 0.f;
#pragma unroll 8
      for (int t = 0; t < 64; t++) zs += kbuf[d2][c2 * 64 + t];
      zred[tid] = zs;
    }
    __syncthreads();
    if (tid < 64)
      atomicAdd(&wKV[(b * NH + hh) * 64 + tid],
                red[tid] + red[tid + 64] + red[tid + 128] + red[tid + 192]);
    if (tid < 8)
      atomicAdd(&wZ[(b * NH + hh) * 8 + tid],
                zred[tid] + zred[tid + 8] + zred[tid + 16] + zred[tid + 24]);
    // next head's kbuf/vbuf writes only happen after all threads pass the
    // barrier above; atomic readers touch red/zred only -> 2 barriers/head safe
  }
}

// ---------------- K3: attention readout (in place) + Wo + residual -> yT ----------------
__global__ __launch_bounds__(256) void k_o(
    const float* __restrict__ x, const float* __restrict__ qphi,
    const float* __restrict__ gamma, const float* __restrict__ beta,
    const float* __restrict__ Wo, const float* __restrict__ bo,
    const float* __restrict__ wmean, const float* __restrict__ wrstd,
    const float* __restrict__ wKV, const float* __restrict__ wZ,
    float* __restrict__ yT) {
  int tid = threadIdx.x;
  int b = blockIdx.x >> 5;
  int l = ((blockIdx.x & 31) << 8) + tid;

  float att[NF];
#pragma unroll
  for (int he = 0; he < NF; he++)
    att[he] = qphi[((size_t)(b * NF + he)) * NL + l];

  for (int hh = 0; hh < NH; hh++) {
    float q8[8];
#pragma unroll
    for (int j = 0; j < 8; j++) q8[j] = att[hh * 8 + j];
    float norm = 1e-6f;
#pragma unroll
    for (int d = 0; d < 8; d++) norm = fmaf(q8[d], wZ[(b * NH + hh) * 8 + d], norm);
    float inv = 1.f / norm;
#pragma unroll
    for (int e = 0; e < 8; e++) {
      float s = 0.f;
#pragma unroll
      for (int d = 0; d < 8; d++)
        s = fmaf(q8[d], wKV[(b * NH + hh) * 64 + d * 8 + e], s);
      att[hh * 8 + e] = s * inv;     // in place: q slice no longer needed
    }
  }

#pragma unroll 4
  for (int f = 0; f < NF; f++) {
    float v = x[((size_t)(b * NF + f)) * NL + l];
    float xn = (v - wmean[b * NF + f]) * wrstd[b * NF + f] * gamma[f] + beta[f];
    float y = xn + bo[f];
#pragma unroll
    for (int he = 0; he < NF; he++)
      y = fmaf(att[he], Wo[f * NF + he], y);
    yT[((size_t)(b * NF + f)) * NL + l] = y;   // (B,F,L) layout, coalesced in l
  }
}

// ---------------- K4: temporal GEMM out2[b,p,f] = sum_l Wlin[p,l]*yT[b,f,l] ----------------
__global__ __launch_bounds__(256) void k_temporal(
    const float* __restrict__ yT, const float* __restrict__ Wlin,
    float* __restrict__ out2) {
  __shared__ float yt[NF * 65];   // +1 pad to break bank conflicts
  __shared__ float wt[NP * 65];
  int tid = threadIdx.x;
  int b = blockIdx.x / SPLIT;
  int kc = blockIdx.x % SPLIT;
  int f0 = (tid & 15) * 4;
  int p0 = (tid >> 4) * 6;
  float acc[4][6];
#pragma unroll
  for (int i = 0; i < 4; i++)
#pragma unroll
    for (int j = 0; j < 6; j++) acc[i][j] = 0.f;

  for (int ks = 0; ks < (NL / SPLIT) / 64; ks++) {
    int l0 = kc * (NL / SPLIT) + ks * 64;
#pragma unroll
    for (int i = 0; i < 4; i++) {            // 64x64 y tile
      int flat4 = tid + i * 256;
      int row = flat4 >> 4, c4 = flat4 & 15;
      float4 v = *(const float4*)(yT + ((size_t)(b * NF + row)) * NL + l0 + c4 * 4);
      float* dst = &yt[row * 65 + c4 * 4];
      dst[0] = v.x; dst[1] = v.y; dst[2] = v.z; dst[3] = v.w;
    }
#pragma unroll
    for (int i = 0; i < 6; i++) {            // 96x64 W tile
      int flat4 = tid + i * 256;
      int row = flat4 >> 4, c4 = flat4 & 15;
      float4 v = *(const float4*)(Wlin + (size_t)row * NL + l0 + c4 * 4);
      float* dst = &wt[row * 65 + c4 * 4];
      dst[0] = v.x; dst[1] = v.y; dst[2] = v.z; dst[3] = v.w;
    }
    __syncthreads();
#pragma unroll 4
    for (int k = 0; k < 64; k++) {
      float yv[4], wv[6];
#pragma unroll
      for (int i = 0; i < 4; i++) yv[i] = yt[(f0 + i) * 65 + k];
#pragma unroll
      for (int j = 0; j < 6; j++) wv[j] = wt[(p0 + j) * 65 + k];
#pragma unroll
      for (int i = 0; i < 4; i++)
#pragma unroll
        for (int j = 0; j < 6; j++)
          acc[i][j] = fmaf(yv[i], wv[j], acc[i][j]);
    }
    __syncthreads();
  }
#pragma unroll
  for (int i = 0; i < 4; i++)
#pragma unroll
    for (int j = 0; j < 6; j++)
      atomicAdd(&out2[((size_t)(b * NP + p0 + j)) * NF + f0 + i], acc[i][j]);
}

// ---------------- K5: +blin, RevIN denorm, projector ----------------
__global__ __launch_bounds__(64) void k_final(
    const float* __restrict__ out2, const float* __restrict__ blin,
    const float* __restrict__ gamma, const float* __restrict__ beta,
    const float* __restrict__ wmean, const float* __restrict__ wstd,
    const float* __restrict__ Wp, const float* __restrict__ bp,
    float* __restrict__ out) {
  int b = blockIdx.x / NP;
  int p = blockIdx.x % NP;
  int f = threadIdx.x;
  float v = out2[((size_t)(b * NP + p)) * NF + f] + blin[p];
  v = (v - beta[f]) / gamma[f];
  v = v * wstd[b * NF + f] + wmean[b * NF + f];
  float s = v * Wp[f];
#pragma unroll
  for (int off = 32; off > 0; off >>= 1)
    s += __shfl_down(s, off, 64);
  if (f == 0) out[blockIdx.x] = s + bp[0];
}

extern "C" void kernel_launch(void* const* d_in, const int* in_sizes, int n_in,
                              void* d_out, int out_size, void* d_ws, size_t ws_size,
                              hipStream_t stream) {
  const float* x     = (const float*)d_in[0];
  const float* gamma = (const float*)d_in[1];
  const float* beta  = (const float*)d_in[2];
  const float* lnw   = (const float*)d_in[3];
  const float* lnb   = (const float*)d_in[4];
  const float* Wq    = (const float*)d_in[5];
  const float* bq    = (const float*)d_in[6];
  const float* Wk    = (const float*)d_in[7];
  const float* bk    = (const float*)d_in[8];
  const float* Wv    = (const float*)d_in[9];
  const float* bv    = (const float*)d_in[10];
  const float* Wo    = (const float*)d_in[11];
  const float* bo    = (const float*)d_in[12];
  const float* Wlin  = (const float*)d_in[13];
  const float* blin  = (const float*)d_in[14];
  const float* Wp    = (const float*)d_in[15];
  const float* bp    = (const float*)d_in[16];
  float* out = (float*)d_out;
  float* ws  = (float*)d_ws;

  float* wmean = ws + WS_MEAN;
  float* wstd  = ws + WS_STD;
  float* wrstd = ws + WS_RSTD;
  float* wKV   = ws + WS_KV;
  float* wZ    = ws + WS_Z;
  float* wout2 = ws + WS_OUT2;
  float* wqphi = ws + WS_QPHI;
  float* wyT   = ws + WS_YT;

  // zero the atomic accumulators: KV, Z, out2 are contiguous [WS_KV, WS_OUT2+B*P*F)
  hipMemsetAsync(wKV, 0, (size_t)(16384 + 2048 + 196608) * sizeof(float), stream);

  k_stats<<<NB * NF, 256, 0, stream>>>(x, wmean, wstd, wrstd);
  k_kvq<<<NB * 32, 256, 0, stream>>>(x, gamma, beta, lnw, lnb, Wq, bq, Wk, bk,
                                     Wv, bv, wmean, wrstd, wqphi, wKV, wZ);
  k_o<<<NB * 32, 256, 0, stream>>>(x, wqphi, gamma, beta, Wo, bo,
                                   wmean, wrstd, wKV, wZ, wyT);
  k_temporal<<<NB * SPLIT, 256, 0, stream>>>(wyT, Wlin, wout2);
  k_final<<<NB * NP, 64, 0, stream>>>(wout2, blin, gamma, beta, wmean, wstd, Wp, bp, out);
}

// Round 4
// 561.923 us; speedup vs baseline: 1.2094x; 1.2094x over previous
//
#include <hip/hip_runtime.h>
#include <cstddef>

#define NB 32
#define NF 64
#define NL 8192
#define NP 96
#define NH 8
#define SPLIT 16

// ws layout in floats:
#define WS_MEAN 0           // 2048
#define WS_STD  2048        // 2048
#define WS_RSTD 4096        // 2048
#define WS_KV   6144        // NB*NH*64 = 16384
#define WS_Z    22528       // NB*NH*8  = 2048
#define WS_OUT2 24576       // NB*NP*NF = 196608
#define WS_QPHI 221184      // NB*NF*NL = 16777216
#define WS_YT   16998400    // NB*NF*NL = 16777216   (total ~135 MB)

// NOTE: parameter names must not collide with .x/.y/.z/.w member tokens
#define FMA4(acc, vec4, a0, a1, a2, a3) \
  acc = fmaf((a3), (vec4).w, fmaf((a2), (vec4).z, fmaf((a1), (vec4).y, fmaf((a0), (vec4).x, (acc)))))

// ---------------- K1: RevIN stats per (b,f) ----------------
__global__ __launch_bounds__(256) void k_stats(const float* __restrict__ x,
                                               float* __restrict__ wmean,
                                               float* __restrict__ wstd,
                                               float* __restrict__ wrstd) {
  int bf = blockIdx.x;
  int tid = threadIdx.x;
  const float4* row4 = (const float4*)(x + (size_t)bf * NL);
  float s1 = 0.f, s2 = 0.f;
#pragma unroll
  for (int i = 0; i < NL / 4 / 256; i++) {
    float4 v = row4[tid + i * 256];
    s1 += v.x + v.y + v.z + v.w;
    s2 += v.x * v.x + v.y * v.y + v.z * v.z + v.w * v.w;
  }
  __shared__ float r1[256], r2[256];
  r1[tid] = s1; r2[tid] = s2;
  __syncthreads();
  for (int off = 128; off > 0; off >>= 1) {
    if (tid < off) { r1[tid] += r1[tid + off]; r2[tid] += r2[tid + off]; }
    __syncthreads();
  }
  if (tid == 0) {
    float m = r1[0] * (1.f / NL);
    float var = (r2[0] - (float)NL * m * m) * (1.f / (NL - 1));
    float sd = sqrtf(fmaxf(var, 0.f)) + 1e-5f;   // eps added to std (torch RevIN)
    wmean[bf] = m;
    wstd[bf] = sd;
    wrstd[bf] = 1.f / sd;
  }
}

// helper: RevIN + LayerNorm into h[64] (registers)
__device__ __forceinline__ void compute_h(
    const float* __restrict__ x, int b, int l,
    const float* __restrict__ gamma, const float* __restrict__ beta,
    const float* __restrict__ lnw, const float* __restrict__ lnb,
    const float* __restrict__ wmean, const float* __restrict__ wrstd,
    float* h) {
  float mu = 0.f;
#pragma unroll
  for (int f = 0; f < NF; f++) {
    float v = x[((size_t)(b * NF + f)) * NL + l];
    v = (v - wmean[b * NF + f]) * wrstd[b * NF + f] * gamma[f] + beta[f];
    h[f] = v;
    mu += v;
  }
  mu *= (1.f / NF);
  float var = 0.f;
#pragma unroll
  for (int f = 0; f < NF; f++) { float d = h[f] - mu; var += d * d; }
  float rs = rsqrtf(var * (1.f / NF) + 1e-5f);
#pragma unroll
  for (int f = 0; f < NF; f++) h[f] = (h[f] - mu) * rs * lnw[f] + lnb[f];
}

// ---------------- K2a: Q projection -> phi(Q) ----------------
__global__ __launch_bounds__(256) void k_q(
    const float* __restrict__ x,
    const float* __restrict__ gamma, const float* __restrict__ beta,
    const float* __restrict__ lnw, const float* __restrict__ lnb,
    const float* __restrict__ Wq, const float* __restrict__ bq,
    const float* __restrict__ wmean, const float* __restrict__ wrstd,
    float* __restrict__ qphi) {
  __shared__ float4 Wq4[1024];          // 16 KB, [o][f4]
  int tid = threadIdx.x;
  int b = blockIdx.x >> 5;
  int l = ((blockIdx.x & 31) << 8) + tid;

  const float4* g = (const float4*)Wq;
#pragma unroll
  for (int i = 0; i < 4; i++) Wq4[tid + i * 256] = g[tid + i * 256];

  float h[NF];
  compute_h(x, b, l, gamma, beta, lnw, lnb, wmean, wrstd, h);
  __syncthreads();

  for (int hh = 0; hh < NH; hh++) {
    float q8[8];
#pragma unroll
    for (int j = 0; j < 8; j++) q8[j] = bq[hh * 8 + j];
#pragma unroll
    for (int f4 = 0; f4 < 16; f4++) {
      float a0 = h[f4 * 4], a1 = h[f4 * 4 + 1], a2 = h[f4 * 4 + 2], a3 = h[f4 * 4 + 3];
#pragma unroll
      for (int j = 0; j < 8; j++) {
        float4 wq_ = Wq4[(hh * 8 + j) * 16 + f4];   // uniform ds_read_b128 broadcast
        FMA4(q8[j], wq_, a0, a1, a2, a3);
      }
    }
#pragma unroll
    for (int j = 0; j < 8; j++) {
      float qq = q8[j];
      qphi[((size_t)(b * NF + hh * 8 + j)) * NL + l] = (qq > 0.f) ? (qq + 1.f) : __expf(qq);
    }
  }
}

// ---------------- K2b: K/V projections + KV,Z accumulation ----------------
__global__ __launch_bounds__(256) void k_kv(
    const float* __restrict__ x,
    const float* __restrict__ gamma, const float* __restrict__ beta,
    const float* __restrict__ lnw, const float* __restrict__ lnb,
    const float* __restrict__ Wk, const float* __restrict__ bk,
    const float* __restrict__ Wv, const float* __restrict__ bv,
    const float* __restrict__ wmean, const float* __restrict__ wrstd,
    float* __restrict__ wKV, float* __restrict__ wZ) {
  __shared__ float4 Wk4[1024], Wv4[1024];                  // 32 KB
  __shared__ __align__(16) float kbuf[8][256], vbuf[8][256]; // 16 KB, [j][l] no pad
  __shared__ float red[256];
  __shared__ float zred[32];
  int tid = threadIdx.x;
  int b = blockIdx.x >> 5;
  int l = ((blockIdx.x & 31) << 8) + tid;

  const float4* gk = (const float4*)Wk;
  const float4* gv = (const float4*)Wv;
#pragma unroll
  for (int i = 0; i < 4; i++) {
    Wk4[tid + i * 256] = gk[tid + i * 256];
    Wv4[tid + i * 256] = gv[tid + i * 256];
  }

  float h[NF];
  compute_h(x, b, l, gamma, beta, lnw, lnb, wmean, wrstd, h);
  __syncthreads();

  int chunk = tid >> 6;          // 0..3
  int dd = (tid & 63) >> 3;      // 0..7
  int ee = tid & 7;              // 0..7

  for (int hh = 0; hh < NH; hh++) {
    float k8[8], v8[8];
#pragma unroll
    for (int j = 0; j < 8; j++) { k8[j] = bk[hh * 8 + j]; v8[j] = bv[hh * 8 + j]; }
#pragma unroll
    for (int f4 = 0; f4 < 16; f4++) {
      float a0 = h[f4 * 4], a1 = h[f4 * 4 + 1], a2 = h[f4 * 4 + 2], a3 = h[f4 * 4 + 3];
#pragma unroll
      for (int j = 0; j < 8; j++) {
        float4 wk_ = Wk4[(hh * 8 + j) * 16 + f4];
        FMA4(k8[j], wk_, a0, a1, a2, a3);
        float4 wv_ = Wv4[(hh * 8 + j) * 16 + f4];
        FMA4(v8[j], wv_, a0, a1, a2, a3);
      }
    }
#pragma unroll
    for (int j = 0; j < 8; j++) {
      float kk = k8[j];
      kbuf[j][tid] = (kk > 0.f) ? (kk + 1.f) : __expf(kk);  // phi = elu+1
      vbuf[j][tid] = v8[j];
    }
    __syncthreads();
    // KV[d][e] partial over this block's 256 l, float4 reads with rotation
    // swizzle so the 8 distinct row addresses never share a bank group.
    const float4* kp = (const float4*)&kbuf[dd][chunk * 64];
    const float4* vp = (const float4*)&vbuf[ee][chunk * 64];
    float s = 0.f;
#pragma unroll
    for (int i = 0; i < 16; i++) {
      float4 ka = kp[(dd + i) & 15];
      float4 va = vp[(ee + i) & 15];
      s = fmaf(ka.x, va.x, s); s = fmaf(ka.y, va.y, s);
      s = fmaf(ka.z, va.z, s); s = fmaf(ka.w, va.w, s);
    }
    red[tid] = s;
    if (tid < 32) {
      int c2 = tid >> 3, d2 = tid & 7;
      const float4* zp = (const float4*)&kbuf[d2][c2 * 64];
      float zsum = 0.f;
#pragma unroll
      for (int i = 0; i < 16; i++) {
        float4 za = zp[(d2 + i) & 15];
        zsum += za.x + za.y + za.z + za.w;
      }
      zred[tid] = zsum;
    }
    __syncthreads();
    if (tid < 64)
      atomicAdd(&wKV[(b * NH + hh) * 64 + tid],
                red[tid] + red[tid + 64] + red[tid + 128] + red[tid + 192]);
    if (tid < 8)
      atomicAdd(&wZ[(b * NH + hh) * 8 + tid],
                zred[tid] + zred[tid + 8] + zred[tid + 16] + zred[tid + 24]);
  }
}

// ---------------- K3: attention readout (in place) + Wo + residual -> yT ----------------
__global__ __launch_bounds__(256) void k_o(
    const float* __restrict__ x, const float* __restrict__ qphi,
    const float* __restrict__ gamma, const float* __restrict__ beta,
    const float* __restrict__ Wo, const float* __restrict__ bo,
    const float* __restrict__ wmean, const float* __restrict__ wrstd,
    const float* __restrict__ wKV, const float* __restrict__ wZ,
    float* __restrict__ yT) {
  __shared__ float4 Wo4[1024];    // 16 KB, [f][he4]
  __shared__ float kvs[NH * 64];  // per-b KV
  __shared__ float zsh[NH * 8];   // per-b Z
  int tid = threadIdx.x;
  int b = blockIdx.x >> 5;
  int l = ((blockIdx.x & 31) << 8) + tid;

  const float4* g = (const float4*)Wo;
#pragma unroll
  for (int i = 0; i < 4; i++) Wo4[tid + i * 256] = g[tid + i * 256];
  if (tid < NH * 64) kvs[tid] = wKV[b * NH * 64 + tid];
  if (tid < NH * 8) zsh[tid] = wZ[b * NH * 8 + tid];

  float att[NF];
#pragma unroll
  for (int he = 0; he < NF; he++)
    att[he] = qphi[((size_t)(b * NF + he)) * NL + l];
  __syncthreads();

  for (int hh = 0; hh < NH; hh++) {
    float norm = 1e-6f;
#pragma unroll
    for (int d = 0; d < 8; d++) norm = fmaf(att[hh * 8 + d], zsh[hh * 8 + d], norm);
    float inv = 1.f / norm;
    float o8[8];
#pragma unroll
    for (int e = 0; e < 8; e++) {
      float s = 0.f;
#pragma unroll
      for (int d = 0; d < 8; d++)
        s = fmaf(att[hh * 8 + d], kvs[hh * 64 + d * 8 + e], s);
      o8[e] = s * inv;
    }
#pragma unroll
    for (int e = 0; e < 8; e++) att[hh * 8 + e] = o8[e];  // in place
  }

#pragma unroll 4
  for (int f = 0; f < NF; f++) {
    float v = x[((size_t)(b * NF + f)) * NL + l];
    float y = (v - wmean[b * NF + f]) * wrstd[b * NF + f] * gamma[f] + beta[f] + bo[f];
#pragma unroll
    for (int q4 = 0; q4 < 16; q4++) {
      float4 wo_ = Wo4[f * 16 + q4];   // uniform broadcast
      FMA4(y, wo_, att[q4 * 4], att[q4 * 4 + 1], att[q4 * 4 + 2], att[q4 * 4 + 3]);
    }
    yT[((size_t)(b * NF + f)) * NL + l] = y;   // (B,F,L) coalesced in l
  }
}

// ---------------- K4: temporal GEMM out2[b,p,f] = sum_l Wlin[p,l]*yT[b,f,l] ----------------
__global__ __launch_bounds__(256) void k_temporal(
    const float* __restrict__ yT, const float* __restrict__ Wlin,
    float* __restrict__ out2) {
  __shared__ float yt[NF * 65];   // +1 pad to break bank conflicts
  __shared__ float wt[NP * 65];
  int tid = threadIdx.x;
  int b = blockIdx.x / SPLIT;
  int kc = blockIdx.x % SPLIT;
  int f0 = (tid & 15) * 4;
  int p0 = (tid >> 4) * 6;
  float acc[4][6];
#pragma unroll
  for (int i = 0; i < 4; i++)
#pragma unroll
    for (int j = 0; j < 6; j++) acc[i][j] = 0.f;

  for (int ks = 0; ks < (NL / SPLIT) / 64; ks++) {
    int l0 = kc * (NL / SPLIT) + ks * 64;
#pragma unroll
    for (int i = 0; i < 4; i++) {            // 64x64 y tile
      int flat4 = tid + i * 256;
      int row = flat4 >> 4, c4 = flat4 & 15;
      float4 v = *(const float4*)(yT + ((size_t)(b * NF + row)) * NL + l0 + c4 * 4);
      float* dst = &yt[row * 65 + c4 * 4];
      dst[0] = v.x; dst[1] = v.y; dst[2] = v.z; dst[3] = v.w;
    }
#pragma unroll
    for (int i = 0; i < 6; i++) {            // 96x64 W tile
      int flat4 = tid + i * 256;
      int row = flat4 >> 4, c4 = flat4 & 15;
      float4 v = *(const float4*)(Wlin + (size_t)row * NL + l0 + c4 * 4);
      float* dst = &wt[row * 65 + c4 * 4];
      dst[0] = v.x; dst[1] = v.y; dst[2] = v.z; dst[3] = v.w;
    }
    __syncthreads();
#pragma unroll 4
    for (int k = 0; k < 64; k++) {
      float yv[4], wv[6];
#pragma unroll
      for (int i = 0; i < 4; i++) yv[i] = yt[(f0 + i) * 65 + k];
#pragma unroll
      for (int j = 0; j < 6; j++) wv[j] = wt[(p0 + j) * 65 + k];
#pragma unroll
      for (int i = 0; i < 4; i++)
#pragma unroll
        for (int j = 0; j < 6; j++)
          acc[i][j] = fmaf(yv[i], wv[j], acc[i][j]);
    }
    __syncthreads();
  }
#pragma unroll
  for (int i = 0; i < 4; i++)
#pragma unroll
    for (int j = 0; j < 6; j++)
      atomicAdd(&out2[((size_t)(b * NP + p0 + j)) * NF + f0 + i], acc[i][j]);
}

// ---------------- K5: +blin, RevIN denorm, projector ----------------
__global__ __launch_bounds__(64) void k_final(
    const float* __restrict__ out2, const float* __restrict__ blin,
    const float* __restrict__ gamma, const float* __restrict__ beta,
    const float* __restrict__ wmean, const float* __restrict__ wstd,
    const float* __restrict__ Wp, const float* __restrict__ bp,
    float* __restrict__ out) {
  int b = blockIdx.x / NP;
  int p = blockIdx.x % NP;
  int f = threadIdx.x;
  float v = out2[((size_t)(b * NP + p)) * NF + f] + blin[p];
  v = (v - beta[f]) / gamma[f];
  v = v * wstd[b * NF + f] + wmean[b * NF + f];
  float s = v * Wp[f];
#pragma unroll
  for (int off = 32; off > 0; off >>= 1)
    s += __shfl_down(s, off, 64);
  if (f == 0) out[blockIdx.x] = s + bp[0];
}

extern "C" void kernel_launch(void* const* d_in, const int* in_sizes, int n_in,
                              void* d_out, int out_size, void* d_ws, size_t ws_size,
                              hipStream_t stream) {
  const float* x     = (const float*)d_in[0];
  const float* gamma = (const float*)d_in[1];
  const float* beta  = (const float*)d_in[2];
  const float* lnw   = (const float*)d_in[3];
  const float* lnb   = (const float*)d_in[4];
  const float* Wq    = (const float*)d_in[5];
  const float* bq    = (const float*)d_in[6];
  const float* Wk    = (const float*)d_in[7];
  const float* bk    = (const float*)d_in[8];
  const float* Wv    = (const float*)d_in[9];
  const float* bv    = (const float*)d_in[10];
  const float* Wo    = (const float*)d_in[11];
  const float* bo    = (const float*)d_in[12];
  const float* Wlin  = (const float*)d_in[13];
  const float* blin  = (const float*)d_in[14];
  const float* Wp    = (const float*)d_in[15];
  const float* bp    = (const float*)d_in[16];
  float* out = (float*)d_out;
  float* ws  = (float*)d_ws;

  float* wmean = ws + WS_MEAN;
  float* wstd  = ws + WS_STD;
  float* wrstd = ws + WS_RSTD;
  float* wKV   = ws + WS_KV;
  float* wZ    = ws + WS_Z;
  float* wout2 = ws + WS_OUT2;
  float* wqphi = ws + WS_QPHI;
  float* wyT   = ws + WS_YT;

  // zero the atomic accumulators: KV, Z, out2 are contiguous [WS_KV, WS_OUT2+B*P*F)
  (void)hipMemsetAsync(wKV, 0, (size_t)(16384 + 2048 + 196608) * sizeof(float), stream);

  k_stats<<<NB * NF, 256, 0, stream>>>(x, wmean, wstd, wrstd);
  k_q<<<NB * 32, 256, 0, stream>>>(x, gamma, beta, lnw, lnb, Wq, bq,
                                   wmean, wrstd, wqphi);
  k_kv<<<NB * 32, 256, 0, stream>>>(x, gamma, beta, lnw, lnb, Wk, bk, Wv, bv,
                                    wmean, wrstd, wKV, wZ);
  k_o<<<NB * 32, 256, 0, stream>>>(x, wqphi, gamma, beta, Wo, bo,
                                   wmean, wrstd, wKV, wZ, wyT);
  k_temporal<<<NB * SPLIT, 256, 0, stream>>>(wyT, Wlin, wout2);
  k_final<<<NB * NP, 64, 0, stream>>>(wout2, blin, gamma, beta, wmean, wstd, Wp, bp, out);
}

// Round 5
// 400.387 us; speedup vs baseline: 1.6973x; 1.4034x over previous
//
#include <hip/hip_runtime.h>
#include <cstddef>

#define NB 32
#define NF 64
#define NL 8192
#define NP 96
#define NH 8
#define SPLIT 16

// ws layout in floats:
#define WS_MEAN 0           // 2048
#define WS_STD  2048        // 2048
#define WS_RSTD 4096        // 2048
#define WS_KV   6144        // NB*NH*64 = 16384
#define WS_Z    22528       // NB*NH*8  = 2048
#define WS_OUT2 24576       // NB*NP*NF = 196608
#define WS_YT   221184      // NB*NF*NL = 16777216 fp32

// ---- bf16 helpers (RNE) ----
__device__ __forceinline__ unsigned short f2bf(float f) {
  unsigned u = __float_as_uint(f);
  unsigned r = u + 0x7FFFu + ((u >> 16) & 1u);
  return (unsigned short)(r >> 16);
}
__device__ __forceinline__ unsigned packbf2(float lo, float hi) {
  return (unsigned)f2bf(lo) | ((unsigned)f2bf(hi) << 16);
}
__device__ __forceinline__ float bflo(unsigned d) { return __uint_as_float(d << 16); }
__device__ __forceinline__ float bfhi(unsigned d) { return __uint_as_float(d & 0xFFFF0000u); }

__device__ __forceinline__ void unp8(uint4 a, uint4 b, float* lo, float* hi) {
  lo[0] = bflo(a.x); hi[0] = bfhi(a.x); lo[1] = bflo(a.y); hi[1] = bfhi(a.y);
  lo[2] = bflo(a.z); hi[2] = bfhi(a.z); lo[3] = bflo(a.w); hi[3] = bfhi(a.w);
  lo[4] = bflo(b.x); hi[4] = bfhi(b.x); lo[5] = bflo(b.y); hi[5] = bfhi(b.y);
  lo[6] = bflo(b.z); hi[6] = bfhi(b.z); lo[7] = bflo(b.w); hi[7] = bfhi(b.w);
}

// ---------------- K1: RevIN stats per (b,f) ----------------
__global__ __launch_bounds__(256) void k_stats(const float* __restrict__ x,
                                               float* __restrict__ wmean,
                                               float* __restrict__ wstd,
                                               float* __restrict__ wrstd) {
  int bf = blockIdx.x;
  int tid = threadIdx.x;
  const float4* row4 = (const float4*)(x + (size_t)bf * NL);
  float s1 = 0.f, s2 = 0.f;
#pragma unroll
  for (int i = 0; i < NL / 4 / 256; i++) {
    float4 v = row4[tid + i * 256];
    s1 += v.x + v.y + v.z + v.w;
    s2 += v.x * v.x + v.y * v.y + v.z * v.z + v.w * v.w;
  }
  __shared__ float r1[256], r2[256];
  r1[tid] = s1; r2[tid] = s2;
  __syncthreads();
  for (int off = 128; off > 0; off >>= 1) {
    if (tid < off) { r1[tid] += r1[tid + off]; r2[tid] += r2[tid + off]; }
    __syncthreads();
  }
  if (tid == 0) {
    float m = r1[0] * (1.f / NL);
    float var = (r2[0] - (float)NL * m * m) * (1.f / (NL - 1));
    float sd = sqrtf(fmaxf(var, 0.f)) + 1e-5f;
    wmean[bf] = m;
    wstd[bf] = sd;
    wrstd[bf] = 1.f / sd;
  }
}

// ---------------- K2: K/V projection GEMM + KV,Z accumulation ----------------
// block: 256 threads, 128 l.  grid: NB*64.
// smem layout (bytes):
//  0      hT2 [32][128] uint (xn bf16 pairs)  16384   } overlaid after GEMM by
//  16384  Wk2 [32][64] uint                    8192   } pK [64][132] us (16896)
//  24576  Wv2 [32][64] uint                    8192   } pV @16896    (16896)
//  33792  SkT [256] f32 (Sk,Tk,Sv,Tv)          1024
//  34816  Tpart [2][4][64] f32                 2048
//  36864  mun [128] f32                         512
//  37376  rsn [128] f32                         512    total 37888
__global__ __launch_bounds__(256, 3) void k_kv(
    const float* __restrict__ x,
    const float* __restrict__ gamma, const float* __restrict__ beta,
    const float* __restrict__ lnw, const float* __restrict__ lnb,
    const float* __restrict__ Wk, const float* __restrict__ bk,
    const float* __restrict__ Wv, const float* __restrict__ bv,
    const float* __restrict__ wmean, const float* __restrict__ wrstd,
    float* __restrict__ wKV, float* __restrict__ wZ) {
  __shared__ __align__(16) char smem[37888];
  unsigned* hT2 = (unsigned*)smem;
  unsigned* Wk2 = (unsigned*)(smem + 16384);
  unsigned* Wv2 = (unsigned*)(smem + 24576);
  unsigned short* pK = (unsigned short*)smem;
  unsigned short* pV = (unsigned short*)(smem + 16896);
  float* SkT   = (float*)(smem + 33792);
  float* Tpart = (float*)(smem + 34816);
  float* mun   = (float*)(smem + 36864);
  float* rsn   = (float*)(smem + 37376);

  const int tid = threadIdx.x;
  const int b = blockIdx.x >> 6;
  const int L0 = (blockIdx.x & 63) * 128;

  // ---- phase 0: stage Wk/Wv (lnw-folded, bf16 pairs) + T partials ----
  {
    int j = tid & 63, g = tid >> 6;
    float tkp = 0.f, tvp = 0.f;
#pragma unroll
    for (int i = 0; i < 8; i++) {
      int f2 = g * 8 + i, f = f2 * 2;
      float2 wk = *(const float2*)&Wk[j * NF + f];
      float2 wv = *(const float2*)&Wv[j * NF + f];
      float w0 = lnw[f], w1 = lnw[f + 1];
      float c0 = lnb[f], c1 = lnb[f + 1];
      Wk2[f2 * 64 + j] = packbf2(wk.x * w0, wk.y * w1);
      Wv2[f2 * 64 + j] = packbf2(wv.x * w0, wv.y * w1);
      tkp += c0 * wk.x + c1 * wk.y;
      tvp += c0 * wv.x + c1 * wv.y;
    }
    Tpart[g * 64 + j] = tkp;
    Tpart[256 + g * 64 + j] = tvp;
  }

  // ---- phase 1: xn (RevIN affine), LN stats, pack to LDS ----
  if (tid < 128) {
    float xn[NF];
    float mu = 0.f;
#pragma unroll
    for (int f = 0; f < NF; f++) {
      float v = x[((size_t)(b * NF + f)) * NL + L0 + tid];
      v = (v - wmean[b * NF + f]) * wrstd[b * NF + f] * gamma[f] + beta[f];
      xn[f] = v; mu += v;
    }
    mu *= (1.f / NF);
    float var = 0.f;
#pragma unroll
    for (int f = 0; f < NF; f++) { float d = xn[f] - mu; var += d * d; }
    float rs = rsqrtf(var * (1.f / NF) + 1e-5f);
    mun[tid] = mu; rsn[tid] = rs;
#pragma unroll
    for (int f2 = 0; f2 < 32; f2++)
      hT2[f2 * 128 + tid] = packbf2(xn[2 * f2], xn[2 * f2 + 1]);
  }
  __syncthreads();

  // ---- finalize S (sum of folded bf16 W) and T (+bias) ----
  if (tid < 128) {
    int m = tid >> 6, j = tid & 63;
    const unsigned* Wm = m ? Wv2 : Wk2;
    float s = 0.f;
#pragma unroll
    for (int f2 = 0; f2 < 32; f2++) { unsigned d = Wm[f2 * 64 + j]; s += bflo(d) + bfhi(d); }
    float t = Tpart[m * 256 + j] + Tpart[m * 256 + 64 + j] +
              Tpart[m * 256 + 128 + j] + Tpart[m * 256 + 192 + j];
    t += m ? bv[j] : bk[j];
    SkT[m * 128 + j] = s;
    SkT[m * 128 + 64 + j] = t;
  }
  __syncthreads();

  // ---- GEMM: 4l x (8jK + 8jV) per thread ----
  const int lt = tid & 31, jg = tid >> 5;
  const int l0 = lt * 4, j0 = jg * 8;
  float ka[4][8], va[4][8];
#pragma unroll
  for (int i = 0; i < 4; i++)
#pragma unroll
    for (int jj = 0; jj < 8; jj++) { ka[i][jj] = 0.f; va[i][jj] = 0.f; }

#pragma unroll 2
  for (int f2 = 0; f2 < 32; f2++) {
    uint4 hA = *(const uint4*)&hT2[f2 * 128 + l0];
    float x0[4] = {bflo(hA.x), bflo(hA.y), bflo(hA.z), bflo(hA.w)};
    float x1[4] = {bfhi(hA.x), bfhi(hA.y), bfhi(hA.z), bfhi(hA.w)};
    uint4 ka4 = *(const uint4*)&Wk2[f2 * 64 + j0];
    uint4 kb4 = *(const uint4*)&Wk2[f2 * 64 + j0 + 4];
    uint4 va4 = *(const uint4*)&Wv2[f2 * 64 + j0];
    uint4 vb4 = *(const uint4*)&Wv2[f2 * 64 + j0 + 4];
    float wk0[8], wk1[8], wv0[8], wv1[8];
    unp8(ka4, kb4, wk0, wk1);
    unp8(va4, vb4, wv0, wv1);
#pragma unroll
    for (int i = 0; i < 4; i++)
#pragma unroll
      for (int jj = 0; jj < 8; jj++) {
        ka[i][jj] = fmaf(x0[i], wk0[jj], ka[i][jj]);
        ka[i][jj] = fmaf(x1[i], wk1[jj], ka[i][jj]);
        va[i][jj] = fmaf(x0[i], wv0[jj], va[i][jj]);
        va[i][jj] = fmaf(x1[i], wv1[jj], va[i][jj]);
      }
  }

  // ---- post-fix: K = rs*(Kraw - mu*Sk) + Tk; phi(K); V likewise ----
  {
    float muv[4], rsv[4];
#pragma unroll
    for (int i = 0; i < 4; i++) { muv[i] = mun[l0 + i]; rsv[i] = rsn[l0 + i]; }
#pragma unroll
    for (int jj = 0; jj < 8; jj++) {
      float Skj = SkT[j0 + jj],       Tkj = SkT[64 + j0 + jj];
      float Svj = SkT[128 + j0 + jj], Tvj = SkT[192 + j0 + jj];
#pragma unroll
      for (int i = 0; i < 4; i++) {
        float kk = rsv[i] * (ka[i][jj] - muv[i] * Skj) + Tkj;
        ka[i][jj] = (kk > 0.f) ? (kk + 1.f) : __expf(kk);
        va[i][jj] = rsv[i] * (va[i][jj] - muv[i] * Svj) + Tvj;
      }
    }
  }
  __syncthreads();   // all hT2/W reads done; safe to overlay with pK/pV

  // ---- stage phi(K), V as bf16 [64 j][132 l] ----
#pragma unroll
  for (int jj = 0; jj < 8; jj++) {
    uint2 dk; dk.x = packbf2(ka[0][jj], ka[1][jj]); dk.y = packbf2(ka[2][jj], ka[3][jj]);
    uint2 dv; dv.x = packbf2(va[0][jj], va[1][jj]); dv.y = packbf2(va[2][jj], va[3][jj]);
    *(uint2*)&pK[(j0 + jj) * 132 + l0] = dk;
    *(uint2*)&pV[(j0 + jj) * 132 + l0] = dv;
  }
  __syncthreads();

  // ---- KV/Z reduction: 2 heads in parallel, 2 l-chunks of 64 ----
  {
    const int hp = tid >> 7, u = tid & 127;
    const int chunk = u >> 6, de = u & 63, dI = de >> 3, eI = de & 7;
#pragma unroll
    for (int h4 = 0; h4 < 4; h4++) {
      int head = h4 * 2 + hp;
      const unsigned short* kr = &pK[(head * 8 + dI) * 132 + chunk * 64];
      const unsigned short* vr = &pV[(head * 8 + eI) * 132 + chunk * 64];
      float acc = 0.f, zacc = 0.f;
#pragma unroll
      for (int i = 0; i < 16; i++) {
        uint2 kd = *(const uint2*)&kr[i * 4];
        uint2 vd = *(const uint2*)&vr[i * 4];
        float k0 = bflo(kd.x), k1 = bfhi(kd.x), k2 = bflo(kd.y), k3 = bfhi(kd.y);
        float v0 = bflo(vd.x), v1 = bfhi(vd.x), v2 = bflo(vd.y), v3 = bfhi(vd.y);
        acc = fmaf(k0, v0, acc); acc = fmaf(k1, v1, acc);
        acc = fmaf(k2, v2, acc); acc = fmaf(k3, v3, acc);
        zacc += (k0 + k1) + (k2 + k3);
      }
      atomicAdd(&wKV[(b * NH + head) * 64 + de], acc);
      if (eI == 0) atomicAdd(&wZ[(b * NH + head) * 8 + dI], zacc);
    }
  }
}

// ---------------- K3: Q GEMM + readout + Wo GEMM + residual -> yT ----------------
// block: 256 threads, 128 l.  grid: NB*64.
// smem:
//  0      hT2 [32][128] uint      16384
//  16384  Wq2 [32][64] uint        8192
//  24576  Wo2 [32][64] uint        8192
//  32768  attS [64][132] ushort   16896  -> 49664
//  49664  kvz [576] f32            2304  -> 51968
//  51968  mun [128]                 512
//  52480  rsn [128]                 512
//  52992  SqTq [128] f32            512
//  53504  Tpart [4][64] f32        1024  -> 54528 total
__global__ __launch_bounds__(256, 3) void k_qy(
    const float* __restrict__ x,
    const float* __restrict__ gamma, const float* __restrict__ beta,
    const float* __restrict__ lnw, const float* __restrict__ lnb,
    const float* __restrict__ Wq, const float* __restrict__ bq,
    const float* __restrict__ Wo, const float* __restrict__ bo,
    const float* __restrict__ wmean, const float* __restrict__ wrstd,
    const float* __restrict__ wKV, const float* __restrict__ wZ,
    float* __restrict__ yT) {
  __shared__ __align__(16) char smem[54528];
  unsigned* hT2 = (unsigned*)smem;
  unsigned* Wq2 = (unsigned*)(smem + 16384);
  unsigned* Wo2 = (unsigned*)(smem + 24576);
  unsigned short* attS = (unsigned short*)(smem + 32768);
  float* kvz   = (float*)(smem + 49664);
  float* mun   = (float*)(smem + 51968);
  float* rsn   = (float*)(smem + 52480);
  float* SqTq  = (float*)(smem + 52992);
  float* Tpart = (float*)(smem + 53504);

  const int tid = threadIdx.x;
  const int b = blockIdx.x >> 6;
  const int L0 = (blockIdx.x & 63) * 128;

  // ---- phase 0: stage Wq (folded), Wo (plain), kvz ----
  {
    int j = tid & 63, g = tid >> 6;
    float tqp = 0.f;
#pragma unroll
    for (int i = 0; i < 8; i++) {
      int f2 = g * 8 + i, f = f2 * 2;
      float2 wq = *(const float2*)&Wq[j * NF + f];
      Wq2[f2 * 64 + j] = packbf2(wq.x * lnw[f], wq.y * lnw[f + 1]);
      tqp += lnb[f] * wq.x + lnb[f + 1] * wq.y;
      // Wo: k-dim is e; j here plays the role of output f
      float2 wo = *(const float2*)&Wo[j * NF + f];
      Wo2[f2 * 64 + j] = packbf2(wo.x, wo.y);
    }
    Tpart[g * 64 + j] = tqp;
    for (int i = tid; i < 576; i += 256)
      kvz[i] = (i < 512) ? wKV[b * 512 + i] : wZ[b * 64 + i - 512];
  }

  // ---- phase 1: xn ----
  if (tid < 128) {
    float xn[NF];
    float mu = 0.f;
#pragma unroll
    for (int f = 0; f < NF; f++) {
      float v = x[((size_t)(b * NF + f)) * NL + L0 + tid];
      v = (v - wmean[b * NF + f]) * wrstd[b * NF + f] * gamma[f] + beta[f];
      xn[f] = v; mu += v;
    }
    mu *= (1.f / NF);
    float var = 0.f;
#pragma unroll
    for (int f = 0; f < NF; f++) { float d = xn[f] - mu; var += d * d; }
    float rs = rsqrtf(var * (1.f / NF) + 1e-5f);
    mun[tid] = mu; rsn[tid] = rs;
#pragma unroll
    for (int f2 = 0; f2 < 32; f2++)
      hT2[f2 * 128 + tid] = packbf2(xn[2 * f2], xn[2 * f2 + 1]);
  }
  __syncthreads();

  if (tid < 64) {
    int j = tid;
    float s = 0.f;
#pragma unroll
    for (int f2 = 0; f2 < 32; f2++) { unsigned d = Wq2[f2 * 64 + j]; s += bflo(d) + bfhi(d); }
    float t = Tpart[j] + Tpart[64 + j] + Tpart[128 + j] + Tpart[192 + j] + bq[j];
    SqTq[j] = s; SqTq[64 + j] = t;
  }
  __syncthreads();

  const int lt = tid & 31, grp = tid >> 5;
  const int l0 = lt * 4;

  // ---- Q-GEMM: 4l x 8j, thread = one head ----
  {
    const int head = grp, j0 = head * 8;
    float qa[4][8];
#pragma unroll
    for (int i = 0; i < 4; i++)
#pragma unroll
      for (int jj = 0; jj < 8; jj++) qa[i][jj] = 0.f;

#pragma unroll 2
    for (int f2 = 0; f2 < 32; f2++) {
      uint4 hA = *(const uint4*)&hT2[f2 * 128 + l0];
      float x0[4] = {bflo(hA.x), bflo(hA.y), bflo(hA.z), bflo(hA.w)};
      float x1[4] = {bfhi(hA.x), bfhi(hA.y), bfhi(hA.z), bfhi(hA.w)};
      uint4 qa4 = *(const uint4*)&Wq2[f2 * 64 + j0];
      uint4 qb4 = *(const uint4*)&Wq2[f2 * 64 + j0 + 4];
      float w0[8], w1[8];
      unp8(qa4, qb4, w0, w1);
#pragma unroll
      for (int i = 0; i < 4; i++)
#pragma unroll
        for (int jj = 0; jj < 8; jj++) {
          qa[i][jj] = fmaf(x0[i], w0[jj], qa[i][jj]);
          qa[i][jj] = fmaf(x1[i], w1[jj], qa[i][jj]);
        }
    }
    // post-fix + phi
    float muv[4], rsv[4];
#pragma unroll
    for (int i = 0; i < 4; i++) { muv[i] = mun[l0 + i]; rsv[i] = rsn[l0 + i]; }
#pragma unroll
    for (int jj = 0; jj < 8; jj++) {
      float Sj = SqTq[j0 + jj], Tj = SqTq[64 + j0 + jj];
#pragma unroll
      for (int i = 0; i < 4; i++) {
        float q = rsv[i] * (qa[i][jj] - muv[i] * Sj) + Tj;
        qa[i][jj] = (q > 0.f) ? (q + 1.f) : __expf(q);
      }
    }
    // readout: att = (qphi . KV) / (qphi . Z + eps)
    float att[4][8], nrm[4];
#pragma unroll
    for (int i = 0; i < 4; i++) {
      nrm[i] = 1e-6f;
#pragma unroll
      for (int e = 0; e < 8; e++) att[i][e] = 0.f;
    }
#pragma unroll
    for (int d = 0; d < 8; d++) {
      float zd = kvz[512 + head * 8 + d];
#pragma unroll
      for (int i = 0; i < 4; i++) nrm[i] = fmaf(qa[i][d], zd, nrm[i]);
#pragma unroll
      for (int e = 0; e < 8; e++) {
        float kvde = kvz[head * 64 + d * 8 + e];
#pragma unroll
        for (int i = 0; i < 4; i++) att[i][e] = fmaf(qa[i][d], kvde, att[i][e]);
      }
    }
#pragma unroll
    for (int i = 0; i < 4; i++) {
      float inv = 1.f / nrm[i];
#pragma unroll
      for (int e = 0; e < 8; e++) att[i][e] *= inv;
    }
    // stage att bf16 [64 e][132 l]
#pragma unroll
    for (int e = 0; e < 8; e++) {
      uint2 da; da.x = packbf2(att[0][e], att[1][e]); da.y = packbf2(att[2][e], att[3][e]);
      *(uint2*)&attS[(head * 8 + e) * 132 + l0] = da;
    }
  }
  __syncthreads();

  // ---- O-GEMM: y[l][f] = sum_e att[l][e]*Wo[f][e], 4l x 8f ----
  {
    const int f0 = grp * 8;
    float ya[4][8];
#pragma unroll
    for (int i = 0; i < 4; i++)
#pragma unroll
      for (int ff = 0; ff < 8; ff++) ya[i][ff] = 0.f;

#pragma unroll 2
    for (int e2 = 0; e2 < 32; e2++) {
      uint2 aA = *(const uint2*)&attS[(2 * e2) * 132 + l0];
      uint2 aB = *(const uint2*)&attS[(2 * e2 + 1) * 132 + l0];
      float a0[4] = {bflo(aA.x), bfhi(aA.x), bflo(aA.y), bfhi(aA.y)};
      float a1[4] = {bflo(aB.x), bfhi(aB.x), bflo(aB.y), bfhi(aB.y)};
      uint4 oa4 = *(const uint4*)&Wo2[e2 * 64 + f0];
      uint4 ob4 = *(const uint4*)&Wo2[e2 * 64 + f0 + 4];
      float w0[8], w1[8];
      unp8(oa4, ob4, w0, w1);
#pragma unroll
      for (int i = 0; i < 4; i++)
#pragma unroll
        for (int ff = 0; ff < 8; ff++) {
          ya[i][ff] = fmaf(a0[i], w0[ff], ya[i][ff]);
          ya[i][ff] = fmaf(a1[i], w1[ff], ya[i][ff]);
        }
    }
    // + xn residual + bo, store fp32 yT (coalesced along l)
#pragma unroll
    for (int f2l = 0; f2l < 4; f2l++) {
      int f2 = grp * 4 + f2l;
      int fA = 2 * f2, fB = 2 * f2 + 1;
      uint4 xA = *(const uint4*)&hT2[f2 * 128 + l0];
      float boA = bo[fA], boB = bo[fB];
      float4 sA, sB;
      sA.x = ya[0][2 * f2l] + bflo(xA.x) + boA;
      sA.y = ya[1][2 * f2l] + bflo(xA.y) + boA;
      sA.z = ya[2][2 * f2l] + bflo(xA.z) + boA;
      sA.w = ya[3][2 * f2l] + bflo(xA.w) + boA;
      sB.x = ya[0][2 * f2l + 1] + bfhi(xA.x) + boB;
      sB.y = ya[1][2 * f2l + 1] + bfhi(xA.y) + boB;
      sB.z = ya[2][2 * f2l + 1] + bfhi(xA.z) + boB;
      sB.w = ya[3][2 * f2l + 1] + bfhi(xA.w) + boB;
      *(float4*)&yT[((size_t)(b * NF + fA)) * NL + L0 + l0] = sA;
      *(float4*)&yT[((size_t)(b * NF + fB)) * NL + L0 + l0] = sB;
    }
  }
}

// ---------------- K4: temporal GEMM out2[b,p,f] = sum_l Wlin[p,l]*yT[b,f,l] ----------------
__global__ __launch_bounds__(256) void k_temporal(
    const float* __restrict__ yT, const float* __restrict__ Wlin,
    float* __restrict__ out2) {
  __shared__ float yt[NF * 65];
  __shared__ float wt[NP * 65];
  int tid = threadIdx.x;
  int b = blockIdx.x / SPLIT;
  int kc = blockIdx.x % SPLIT;
  int f0 = (tid & 15) * 4;
  int p0 = (tid >> 4) * 6;
  float acc[4][6];
#pragma unroll
  for (int i = 0; i < 4; i++)
#pragma unroll
    for (int j = 0; j < 6; j++) acc[i][j] = 0.f;

  for (int ks = 0; ks < (NL / SPLIT) / 64; ks++) {
    int l0 = kc * (NL / SPLIT) + ks * 64;
#pragma unroll
    for (int i = 0; i < 4; i++) {
      int flat4 = tid + i * 256;
      int row = flat4 >> 4, c4 = flat4 & 15;
      float4 v = *(const float4*)(yT + ((size_t)(b * NF + row)) * NL + l0 + c4 * 4);
      float* dst = &yt[row * 65 + c4 * 4];
      dst[0] = v.x; dst[1] = v.y; dst[2] = v.z; dst[3] = v.w;
    }
#pragma unroll
    for (int i = 0; i < 6; i++) {
      int flat4 = tid + i * 256;
      int row = flat4 >> 4, c4 = flat4 & 15;
      float4 v = *(const float4*)(Wlin + (size_t)row * NL + l0 + c4 * 4);
      float* dst = &wt[row * 65 + c4 * 4];
      dst[0] = v.x; dst[1] = v.y; dst[2] = v.z; dst[3] = v.w;
    }
    __syncthreads();
#pragma unroll 4
    for (int k = 0; k < 64; k++) {
      float yv[4], wv[6];
#pragma unroll
      for (int i = 0; i < 4; i++) yv[i] = yt[(f0 + i) * 65 + k];
#pragma unroll
      for (int j = 0; j < 6; j++) wv[j] = wt[(p0 + j) * 65 + k];
#pragma unroll
      for (int i = 0; i < 4; i++)
#pragma unroll
        for (int j = 0; j < 6; j++)
          acc[i][j] = fmaf(yv[i], wv[j], acc[i][j]);
    }
    __syncthreads();
  }
#pragma unroll
  for (int i = 0; i < 4; i++)
#pragma unroll
    for (int j = 0; j < 6; j++)
      atomicAdd(&out2[((size_t)(b * NP + p0 + j)) * NF + f0 + i], acc[i][j]);
}

// ---------------- K5: +blin, RevIN denorm, projector ----------------
__global__ __launch_bounds__(64) void k_final(
    const float* __restrict__ out2, const float* __restrict__ blin,
    const float* __restrict__ gamma, const float* __restrict__ beta,
    const float* __restrict__ wmean, const float* __restrict__ wstd,
    const float* __restrict__ Wp, const float* __restrict__ bp,
    float* __restrict__ out) {
  int b = blockIdx.x / NP;
  int p = blockIdx.x % NP;
  int f = threadIdx.x;
  float v = out2[((size_t)(b * NP + p)) * NF + f] + blin[p];
  v = (v - beta[f]) / gamma[f];
  v = v * wstd[b * NF + f] + wmean[b * NF + f];
  float s = v * Wp[f];
#pragma unroll
  for (int off = 32; off > 0; off >>= 1)
    s += __shfl_down(s, off, 64);
  if (f == 0) out[blockIdx.x] = s + bp[0];
}

extern "C" void kernel_launch(void* const* d_in, const int* in_sizes, int n_in,
                              void* d_out, int out_size, void* d_ws, size_t ws_size,
                              hipStream_t stream) {
  const float* x     = (const float*)d_in[0];
  const float* gamma = (const float*)d_in[1];
  const float* beta  = (const float*)d_in[2];
  const float* lnw   = (const float*)d_in[3];
  const float* lnb   = (const float*)d_in[4];
  const float* Wq    = (const float*)d_in[5];
  const float* bq    = (const float*)d_in[6];
  const float* Wk    = (const float*)d_in[7];
  const float* bk    = (const float*)d_in[8];
  const float* Wv    = (const float*)d_in[9];
  const float* bv    = (const float*)d_in[10];
  const float* Wo    = (const float*)d_in[11];
  const float* bo    = (const float*)d_in[12];
  const float* Wlin  = (const float*)d_in[13];
  const float* blin  = (const float*)d_in[14];
  const float* Wp    = (const float*)d_in[15];
  const float* bp    = (const float*)d_in[16];
  float* out = (float*)d_out;
  float* ws  = (float*)d_ws;

  float* wmean = ws + WS_MEAN;
  float* wstd  = ws + WS_STD;
  float* wrstd = ws + WS_RSTD;
  float* wKV   = ws + WS_KV;
  float* wZ    = ws + WS_Z;
  float* wout2 = ws + WS_OUT2;
  float* wyT   = ws + WS_YT;

  (void)hipMemsetAsync(wKV, 0, (size_t)(16384 + 2048 + 196608) * sizeof(float), stream);

  k_stats<<<NB * NF, 256, 0, stream>>>(x, wmean, wstd, wrstd);
  k_kv<<<NB * 64, 256, 0, stream>>>(x, gamma, beta, lnw, lnb, Wk, bk, Wv, bv,
                                    wmean, wrstd, wKV, wZ);
  k_qy<<<NB * 64, 256, 0, stream>>>(x, gamma, beta, lnw, lnb, Wq, bq, Wo, bo,
                                    wmean, wrstd, wKV, wZ, wyT);
  k_temporal<<<NB * SPLIT, 256, 0, stream>>>(wyT, Wlin, wout2);
  k_final<<<NB * NP, 64, 0, stream>>>(wout2, blin, gamma, beta, wmean, wstd, Wp, bp, out);
}

// Round 6
// 298.037 us; speedup vs baseline: 2.2802x; 1.3434x over previous
//
#include <hip/hip_runtime.h>
#include <cstddef>

#define NB 32
#define NF 64
#define NL 8192
#define NP 96
#define NH 8
#define SPLIT 16

// ws layout in floats:
#define WS_MEAN 0           // 2048
#define WS_STD  2048        // 2048
#define WS_RSTD 4096        // 2048
#define WS_KV   6144        // NB*NH*64 = 16384
#define WS_Z    22528       // NB*NH*8  = 2048
#define WS_OUT2 24576       // NB*NP*NF = 196608
#define WS_YT   221184      // NB*NF*NL = 16777216 fp32

typedef __bf16 bfx8 __attribute__((ext_vector_type(8)));
typedef float f32x4 __attribute__((ext_vector_type(4)));
#define MFMA16(a, b, c) __builtin_amdgcn_mfma_f32_16x16x32_bf16((a), (b), (c), 0, 0, 0)

// ---- bf16 helpers (RNE) ----
__device__ __forceinline__ unsigned short f2bf(float f) {
  unsigned u = __float_as_uint(f);
  unsigned r = u + 0x7FFFu + ((u >> 16) & 1u);
  return (unsigned short)(r >> 16);
}
__device__ __forceinline__ unsigned packbf2(float lo, float hi) {
  return (unsigned)f2bf(lo) | ((unsigned)f2bf(hi) << 16);
}
__device__ __forceinline__ float bflo(unsigned d) { return __uint_as_float(d << 16); }
__device__ __forceinline__ float bfhi(unsigned d) { return __uint_as_float(d & 0xFFFF0000u); }
__device__ __forceinline__ float bf1(unsigned short s) { return __uint_as_float(((unsigned)s) << 16); }

__device__ __forceinline__ bfx8 ldfrag(const unsigned short* p) {
  uint4 u = *(const uint4*)p;
  return __builtin_bit_cast(bfx8, u);
}

// ---------------- K1: RevIN stats per (b,f) ----------------
__global__ __launch_bounds__(256) void k_stats(const float* __restrict__ x,
                                               float* __restrict__ wmean,
                                               float* __restrict__ wstd,
                                               float* __restrict__ wrstd) {
  int bf = blockIdx.x;
  int tid = threadIdx.x;
  const float4* row4 = (const float4*)(x + (size_t)bf * NL);
  float s1 = 0.f, s2 = 0.f;
#pragma unroll
  for (int i = 0; i < NL / 4 / 256; i++) {
    float4 v = row4[tid + i * 256];
    s1 += v.x + v.y + v.z + v.w;
    s2 += v.x * v.x + v.y * v.y + v.z * v.z + v.w * v.w;
  }
  __shared__ float r1[256], r2[256];
  r1[tid] = s1; r2[tid] = s2;
  __syncthreads();
  for (int off = 128; off > 0; off >>= 1) {
    if (tid < off) { r1[tid] += r1[tid + off]; r2[tid] += r2[tid + off]; }
    __syncthreads();
  }
  if (tid == 0) {
    float m = r1[0] * (1.f / NL);
    float var = (r2[0] - (float)NL * m * m) * (1.f / (NL - 1));
    float sd = sqrtf(fmaxf(var, 0.f)) + 1e-5f;
    wmean[bf] = m;
    wstd[bf] = sd;
    wrstd[bf] = 1.f / sd;
  }
}

// ---------------- K2: K/V projection (MFMA) + KV,Z accumulation (MFMA) ----------------
// 256 threads, 128 l per block, grid NB*64.  LDS 40960 B -> 4 blocks/CU.
__global__ __launch_bounds__(256, 4) void k_kv(
    const float* __restrict__ x,
    const float* __restrict__ gamma, const float* __restrict__ beta,
    const float* __restrict__ lnw, const float* __restrict__ lnb,
    const float* __restrict__ Wk, const float* __restrict__ bk,
    const float* __restrict__ Wv, const float* __restrict__ bv,
    const float* __restrict__ wmean, const float* __restrict__ wrstd,
    float* __restrict__ wKV, float* __restrict__ wZ) {
  __shared__ __align__(16) char smem[40960];
  unsigned short* hA  = (unsigned short*)smem;            // [128][72] xn bf16
  unsigned short* WkB = (unsigned short*)(smem + 18432);  // [64 j][72 f] folded
  unsigned short* WvB = (unsigned short*)(smem + 27648);  // [64 j][72 f] folded
  unsigned short* pK  = (unsigned short*)smem;            // overlay: [64 j][136 l]
  unsigned short* pV  = (unsigned short*)(smem + 17408);  // overlay: [64 j][136 l]
  float* SkT   = (float*)(smem + 36864);  // [256] Sk|Tk|Sv|Tv
  float* Tpart = (float*)(smem + 37888);  // [2][4][64]
  float* mun   = (float*)(smem + 39936);  // [128]
  float* rsn   = (float*)(smem + 40448);  // [128]

  const int tid = threadIdx.x;
  const int b = blockIdx.x >> 6;
  const int L0 = (blockIdx.x & 63) * 128;
  const int lane = tid & 63, wv = tid >> 6;
  const int mm = lane & 15, qd = lane >> 4;

  // ---- phase 0: stage Wk/Wv rows (lnw-folded bf16) + T partials (coalesced) ----
  {
    int jj = tid >> 2, g = tid & 3;      // row j, f-quarter
    int f0 = g * 16;
    float tkp = 0.f, tvp = 0.f;
#pragma unroll
    for (int i = 0; i < 4; i++) {
      int f = f0 + i * 4;
      float4 wk4 = *(const float4*)&Wk[jj * NF + f];
      float4 wv4 = *(const float4*)&Wv[jj * NF + f];
      float4 lw  = *(const float4*)&lnw[f];
      float4 lb  = *(const float4*)&lnb[f];
      uint2 pk2, pv2;
      pk2.x = packbf2(wk4.x * lw.x, wk4.y * lw.y);
      pk2.y = packbf2(wk4.z * lw.z, wk4.w * lw.w);
      pv2.x = packbf2(wv4.x * lw.x, wv4.y * lw.y);
      pv2.y = packbf2(wv4.z * lw.z, wv4.w * lw.w);
      *(uint2*)&WkB[jj * 72 + f] = pk2;
      *(uint2*)&WvB[jj * 72 + f] = pv2;
      tkp += lb.x * wk4.x + lb.y * wk4.y + lb.z * wk4.z + lb.w * wk4.w;
      tvp += lb.x * wv4.x + lb.y * wv4.y + lb.z * wv4.z + lb.w * wv4.w;
    }
    Tpart[g * 64 + jj] = tkp;
    Tpart[256 + g * 64 + jj] = tvp;
  }

  // ---- phase 1: xn (RevIN affine), LN stats, row-major bf16 pack ----
  if (tid < 128) {
    float xn[NF];
    float mu = 0.f;
#pragma unroll
    for (int f = 0; f < NF; f++) {
      float v = x[((size_t)(b * NF + f)) * NL + L0 + tid];
      v = (v - wmean[b * NF + f]) * wrstd[b * NF + f] * gamma[f] + beta[f];
      xn[f] = v; mu += v;
    }
    mu *= (1.f / NF);
    float var = 0.f;
#pragma unroll
    for (int f = 0; f < NF; f++) { float d = xn[f] - mu; var += d * d; }
    float rs = rsqrtf(var * (1.f / NF) + 1e-5f);
    mun[tid] = mu; rsn[tid] = rs;
    unsigned* hrow = (unsigned*)&hA[tid * 72];
#pragma unroll
    for (int f2 = 0; f2 < 32; f2++)
      hrow[f2] = packbf2(xn[2 * f2], xn[2 * f2 + 1]);
  }
  __syncthreads();

  // ---- S (sum of folded bf16 row) and T (+bias) finalize ----
  if (tid < 128) {
    int sel = tid >> 6, j = tid & 63;
    const unsigned* wr = (const unsigned*)((sel ? WvB : WkB) + j * 72);
    float s = 0.f;
#pragma unroll
    for (int i = 0; i < 32; i++) { unsigned d = wr[i]; s += bflo(d) + bfhi(d); }
    float t = Tpart[sel * 256 + j] + Tpart[sel * 256 + 64 + j] +
              Tpart[sel * 256 + 128 + j] + Tpart[sel * 256 + 192 + j];
    t += sel ? bv[j] : bk[j];
    SkT[sel * 128 + j] = s;
    SkT[sel * 128 + 64 + j] = t;
  }
  __syncthreads();

  // ---- projection MFMA: out[l][j], wave handles 32 l x 64 j ----
  const f32x4 fz = {0.f, 0.f, 0.f, 0.f};
  f32x4 kacc[2][4], vacc[2][4];
#pragma unroll
  for (int i = 0; i < 2; i++)
#pragma unroll
    for (int jt = 0; jt < 4; jt++) { kacc[i][jt] = fz; vacc[i][jt] = fz; }

#pragma unroll
  for (int kc = 0; kc < 2; kc++) {
    bfx8 a0 = ldfrag(&hA[(wv * 32 + mm) * 72 + kc * 32 + qd * 8]);
    bfx8 a1 = ldfrag(&hA[(wv * 32 + 16 + mm) * 72 + kc * 32 + qd * 8]);
#pragma unroll
    for (int jt = 0; jt < 4; jt++) {
      bfx8 bkf = ldfrag(&WkB[(jt * 16 + mm) * 72 + kc * 32 + qd * 8]);
      bfx8 bvf = ldfrag(&WvB[(jt * 16 + mm) * 72 + kc * 32 + qd * 8]);
      kacc[0][jt] = MFMA16(a0, bkf, kacc[0][jt]);
      kacc[1][jt] = MFMA16(a1, bkf, kacc[1][jt]);
      vacc[0][jt] = MFMA16(a0, bvf, vacc[0][jt]);
      vacc[1][jt] = MFMA16(a1, bvf, vacc[1][jt]);
    }
  }

  // ---- postfix: K = rs*(raw - mu*Sk) + Tk -> phi;  V likewise (no phi) ----
#pragma unroll
  for (int lt2 = 0; lt2 < 2; lt2++) {
    float4 mu4 = *(const float4*)&mun[wv * 32 + lt2 * 16 + qd * 4];
    float4 rs4 = *(const float4*)&rsn[wv * 32 + lt2 * 16 + qd * 4];
    float muv[4] = {mu4.x, mu4.y, mu4.z, mu4.w};
    float rsv[4] = {rs4.x, rs4.y, rs4.z, rs4.w};
#pragma unroll
    for (int jt = 0; jt < 4; jt++) {
      int j = jt * 16 + mm;
      float Sk = SkT[j], Tk = SkT[64 + j], Sv = SkT[128 + j], Tv = SkT[192 + j];
#pragma unroll
      for (int r = 0; r < 4; r++) {
        float kk = rsv[r] * (kacc[lt2][jt][r] - muv[r] * Sk) + Tk;
        kacc[lt2][jt][r] = (kk > 0.f) ? (kk + 1.f) : __expf(kk);
        vacc[lt2][jt][r] = rsv[r] * (vacc[lt2][jt][r] - muv[r] * Sv) + Tv;
      }
    }
  }
  __syncthreads();   // hA/WkB/WvB dead -> overlay with pK/pV

  // ---- pack phi(K), V into [64 j][136 l] bf16 ----
#pragma unroll
  for (int lt2 = 0; lt2 < 2; lt2++) {
    int l0 = wv * 32 + lt2 * 16 + qd * 4;
#pragma unroll
    for (int jt = 0; jt < 4; jt++) {
      int j = jt * 16 + mm;
      uint2 dk, dv;
      dk.x = packbf2(kacc[lt2][jt][0], kacc[lt2][jt][1]);
      dk.y = packbf2(kacc[lt2][jt][2], kacc[lt2][jt][3]);
      dv.x = packbf2(vacc[lt2][jt][0], vacc[lt2][jt][1]);
      dv.y = packbf2(vacc[lt2][jt][2], vacc[lt2][jt][3]);
      *(uint2*)&pK[j * 136 + l0] = dk;
      *(uint2*)&pV[j * 136 + l0] = dv;
    }
  }
  __syncthreads();

  // ---- KV reduction MFMA: wave = head pair {2wv, 2wv+1}; A=phi(K)^T, B=V ----
  {
    f32x4 racc = fz;
#pragma unroll
    for (int kb = 0; kb < 4; kb++) {
      bfx8 ak = ldfrag(&pK[(wv * 16 + mm) * 136 + kb * 32 + qd * 8]);
      bfx8 bv8 = ldfrag(&pV[(wv * 16 + mm) * 136 + kb * 32 + qd * 8]);
      racc = MFMA16(ak, bv8, racc);
    }
    int eh = mm >> 3, e = mm & 7;
#pragma unroll
    for (int r = 0; r < 4; r++) {
      int row = qd * 4 + r;
      if ((row >> 3) == eh)
        atomicAdd(&wKV[(b * NH + wv * 2 + eh) * 64 + (row & 7) * 8 + e], racc[r]);
    }
  }
  // ---- Z: row sums of pK ----
  if (tid < 64) {
    const unsigned* kr = (const unsigned*)&pK[tid * 136];
    float zs = 0.f;
#pragma unroll
    for (int i = 0; i < 64; i++) { unsigned d = kr[i]; zs += bflo(d) + bfhi(d); }
    atomicAdd(&wZ[b * 64 + tid], zs);
  }
}

// ---------------- K3: Q MFMA + readout (in-place LDS) + O MFMA + residual -> yT ----------------
// 256 threads, 128 l, grid NB*64.  LDS 60160 B -> 2 blocks/CU.
__global__ __launch_bounds__(256, 2) void k_qy(
    const float* __restrict__ x,
    const float* __restrict__ gamma, const float* __restrict__ beta,
    const float* __restrict__ lnw, const float* __restrict__ lnb,
    const float* __restrict__ Wq, const float* __restrict__ bq,
    const float* __restrict__ Wo, const float* __restrict__ bo,
    const float* __restrict__ wmean, const float* __restrict__ wrstd,
    const float* __restrict__ wKV, const float* __restrict__ wZ,
    float* __restrict__ yT) {
  __shared__ __align__(16) char smem[60160];
  unsigned short* hA  = (unsigned short*)smem;             // [128][72] xn bf16
  unsigned short* WqB = (unsigned short*)(smem + 18432);   // [64 j][72 f] folded
  unsigned short* WoB = (unsigned short*)(smem + 27648);   // [64 f][72 e]
  unsigned short* qaA = (unsigned short*)(smem + 36864);   // [128 l][72] phi(Q) -> att
  float* kvz   = (float*)(smem + 55296);  // [576]
  float* mun   = (float*)(smem + 57600);
  float* rsn   = (float*)(smem + 58112);
  float* SqTq  = (float*)(smem + 58624);  // [128]
  float* Tpart = (float*)(smem + 59136);  // [4][64]

  const int tid = threadIdx.x;
  const int b = blockIdx.x >> 6;
  const int L0 = (blockIdx.x & 63) * 128;
  const int lane = tid & 63, wv = tid >> 6;
  const int mm = lane & 15, qd = lane >> 4;

  // ---- phase 0: stage Wq (folded) + Wo rows + kvz ----
  {
    int jj = tid >> 2, g = tid & 3;
    int f0 = g * 16;
    float tqp = 0.f;
#pragma unroll
    for (int i = 0; i < 4; i++) {
      int f = f0 + i * 4;
      float4 wq4 = *(const float4*)&Wq[jj * NF + f];
      float4 wo4 = *(const float4*)&Wo[jj * NF + f];
      float4 lw  = *(const float4*)&lnw[f];
      float4 lb  = *(const float4*)&lnb[f];
      uint2 pq2, po2;
      pq2.x = packbf2(wq4.x * lw.x, wq4.y * lw.y);
      pq2.y = packbf2(wq4.z * lw.z, wq4.w * lw.w);
      po2.x = packbf2(wo4.x, wo4.y);
      po2.y = packbf2(wo4.z, wo4.w);
      *(uint2*)&WqB[jj * 72 + f] = pq2;
      *(uint2*)&WoB[jj * 72 + f] = po2;
      tqp += lb.x * wq4.x + lb.y * wq4.y + lb.z * wq4.z + lb.w * wq4.w;
    }
    Tpart[g * 64 + jj] = tqp;
  }
  for (int i = tid; i < 576; i += 256)
    kvz[i] = (i < 512) ? wKV[b * 512 + i] : wZ[b * 64 + i - 512];

  // ---- phase 1: xn ----
  if (tid < 128) {
    float xn[NF];
    float mu = 0.f;
#pragma unroll
    for (int f = 0; f < NF; f++) {
      float v = x[((size_t)(b * NF + f)) * NL + L0 + tid];
      v = (v - wmean[b * NF + f]) * wrstd[b * NF + f] * gamma[f] + beta[f];
      xn[f] = v; mu += v;
    }
    mu *= (1.f / NF);
    float var = 0.f;
#pragma unroll
    for (int f = 0; f < NF; f++) { float d = xn[f] - mu; var += d * d; }
    float rs = rsqrtf(var * (1.f / NF) + 1e-5f);
    mun[tid] = mu; rsn[tid] = rs;
    unsigned* hrow = (unsigned*)&hA[tid * 72];
#pragma unroll
    for (int f2 = 0; f2 < 32; f2++)
      hrow[f2] = packbf2(xn[2 * f2], xn[2 * f2 + 1]);
  }
  __syncthreads();

  if (tid < 64) {
    const unsigned* wr = (const unsigned*)(WqB + tid * 72);
    float s = 0.f;
#pragma unroll
    for (int i = 0; i < 32; i++) { unsigned d = wr[i]; s += bflo(d) + bfhi(d); }
    float t = Tpart[tid] + Tpart[64 + tid] + Tpart[128 + tid] + Tpart[192 + tid] + bq[tid];
    SqTq[tid] = s; SqTq[64 + tid] = t;
  }
  __syncthreads();

  const f32x4 fz = {0.f, 0.f, 0.f, 0.f};

  // ---- Q-MFMA ----
  {
    f32x4 qacc[2][4];
#pragma unroll
    for (int i = 0; i < 2; i++)
#pragma unroll
      for (int jt = 0; jt < 4; jt++) qacc[i][jt] = fz;
#pragma unroll
    for (int kc = 0; kc < 2; kc++) {
      bfx8 a0 = ldfrag(&hA[(wv * 32 + mm) * 72 + kc * 32 + qd * 8]);
      bfx8 a1 = ldfrag(&hA[(wv * 32 + 16 + mm) * 72 + kc * 32 + qd * 8]);
#pragma unroll
      for (int jt = 0; jt < 4; jt++) {
        bfx8 bqf = ldfrag(&WqB[(jt * 16 + mm) * 72 + kc * 32 + qd * 8]);
        qacc[0][jt] = MFMA16(a0, bqf, qacc[0][jt]);
        qacc[1][jt] = MFMA16(a1, bqf, qacc[1][jt]);
      }
    }
    // postfix + phi, scatter to qaA rows [l][j]
#pragma unroll
    for (int lt2 = 0; lt2 < 2; lt2++) {
      float4 mu4 = *(const float4*)&mun[wv * 32 + lt2 * 16 + qd * 4];
      float4 rs4 = *(const float4*)&rsn[wv * 32 + lt2 * 16 + qd * 4];
      float muv[4] = {mu4.x, mu4.y, mu4.z, mu4.w};
      float rsv[4] = {rs4.x, rs4.y, rs4.z, rs4.w};
      int l0 = wv * 32 + lt2 * 16 + qd * 4;
#pragma unroll
      for (int jt = 0; jt < 4; jt++) {
        int j = jt * 16 + mm;
        float Sj = SqTq[j], Tj = SqTq[64 + j];
#pragma unroll
        for (int r = 0; r < 4; r++) {
          float q = rsv[r] * (qacc[lt2][jt][r] - muv[r] * Sj) + Tj;
          q = (q > 0.f) ? (q + 1.f) : __expf(q);
          qaA[(l0 + r) * 72 + j] = f2bf(q);
        }
      }
    }
  }
  __syncthreads();

  // ---- readout in place: thread = (4 l, 1 head) tile of qaA ----
  {
    int lt = tid & 31, hd = tid >> 5;
    int lbase = lt * 4;
    float qv[4][8];
#pragma unroll
    for (int i = 0; i < 4; i++) {
      uint4 u = *(const uint4*)&qaA[(lbase + i) * 72 + hd * 8];
      qv[i][0] = bflo(u.x); qv[i][1] = bfhi(u.x);
      qv[i][2] = bflo(u.y); qv[i][3] = bfhi(u.y);
      qv[i][4] = bflo(u.z); qv[i][5] = bfhi(u.z);
      qv[i][6] = bflo(u.w); qv[i][7] = bfhi(u.w);
    }
    float att[4][8], nrm[4];
#pragma unroll
    for (int i = 0; i < 4; i++) {
      nrm[i] = 1e-6f;
#pragma unroll
      for (int e = 0; e < 8; e++) att[i][e] = 0.f;
    }
#pragma unroll
    for (int d = 0; d < 8; d++) {
      float zd = kvz[512 + hd * 8 + d];
      float4 kva = *(const float4*)&kvz[hd * 64 + d * 8];
      float4 kvb = *(const float4*)&kvz[hd * 64 + d * 8 + 4];
#pragma unroll
      for (int i = 0; i < 4; i++) {
        float qq = qv[i][d];
        nrm[i] = fmaf(qq, zd, nrm[i]);
        att[i][0] = fmaf(qq, kva.x, att[i][0]);
        att[i][1] = fmaf(qq, kva.y, att[i][1]);
        att[i][2] = fmaf(qq, kva.z, att[i][2]);
        att[i][3] = fmaf(qq, kva.w, att[i][3]);
        att[i][4] = fmaf(qq, kvb.x, att[i][4]);
        att[i][5] = fmaf(qq, kvb.y, att[i][5]);
        att[i][6] = fmaf(qq, kvb.z, att[i][6]);
        att[i][7] = fmaf(qq, kvb.w, att[i][7]);
      }
    }
#pragma unroll
    for (int i = 0; i < 4; i++) {
      float inv = 1.f / nrm[i];
      uint4 o;
      o.x = packbf2(att[i][0] * inv, att[i][1] * inv);
      o.y = packbf2(att[i][2] * inv, att[i][3] * inv);
      o.z = packbf2(att[i][4] * inv, att[i][5] * inv);
      o.w = packbf2(att[i][6] * inv, att[i][7] * inv);
      *(uint4*)&qaA[(lbase + i) * 72 + hd * 8] = o;
    }
  }
  __syncthreads();

  // ---- O-MFMA: y[l][f] = att[l][e] . Wo[f][e] ----
  {
    f32x4 yacc[2][4];
#pragma unroll
    for (int i = 0; i < 2; i++)
#pragma unroll
      for (int ft = 0; ft < 4; ft++) yacc[i][ft] = fz;
#pragma unroll
    for (int ec = 0; ec < 2; ec++) {
      bfx8 a0 = ldfrag(&qaA[(wv * 32 + mm) * 72 + ec * 32 + qd * 8]);
      bfx8 a1 = ldfrag(&qaA[(wv * 32 + 16 + mm) * 72 + ec * 32 + qd * 8]);
#pragma unroll
      for (int ft = 0; ft < 4; ft++) {
        bfx8 bof = ldfrag(&WoB[(ft * 16 + mm) * 72 + ec * 32 + qd * 8]);
        yacc[0][ft] = MFMA16(a0, bof, yacc[0][ft]);
        yacc[1][ft] = MFMA16(a1, bof, yacc[1][ft]);
      }
    }
    // epilogue: + xn residual + bo -> yT fp32 (B,F,L)
#pragma unroll
    for (int lt2 = 0; lt2 < 2; lt2++) {
      int l0 = wv * 32 + lt2 * 16 + qd * 4;
#pragma unroll
      for (int ft = 0; ft < 4; ft++) {
        int ff = ft * 16 + mm;
        float bof = bo[ff];
        float4 o;
        o.x = yacc[lt2][ft][0] + bf1(hA[(l0 + 0) * 72 + ff]) + bof;
        o.y = yacc[lt2][ft][1] + bf1(hA[(l0 + 1) * 72 + ff]) + bof;
        o.z = yacc[lt2][ft][2] + bf1(hA[(l0 + 2) * 72 + ff]) + bof;
        o.w = yacc[lt2][ft][3] + bf1(hA[(l0 + 3) * 72 + ff]) + bof;
        *(float4*)&yT[((size_t)(b * NF + ff)) * NL + L0 + l0] = o;
      }
    }
  }
}

// ---------------- K4: temporal GEMM out2[b,p,f] = sum_l Wlin[p,l]*yT[b,f,l] ----------------
__global__ __launch_bounds__(256) void k_temporal(
    const float* __restrict__ yT, const float* __restrict__ Wlin,
    float* __restrict__ out2) {
  __shared__ float yt[NF * 65];
  __shared__ float wt[NP * 65];
  int tid = threadIdx.x;
  int b = blockIdx.x / SPLIT;
  int kc = blockIdx.x % SPLIT;
  int f0 = (tid & 15) * 4;
  int p0 = (tid >> 4) * 6;
  float acc[4][6];
#pragma unroll
  for (int i = 0; i < 4; i++)
#pragma unroll
    for (int j = 0; j < 6; j++) acc[i][j] = 0.f;

  for (int ks = 0; ks < (NL / SPLIT) / 64; ks++) {
    int l0 = kc * (NL / SPLIT) + ks * 64;
#pragma unroll
    for (int i = 0; i < 4; i++) {
      int flat4 = tid + i * 256;
      int row = flat4 >> 4, c4 = flat4 & 15;
      float4 v = *(const float4*)(yT + ((size_t)(b * NF + row)) * NL + l0 + c4 * 4);
      float* dst = &yt[row * 65 + c4 * 4];
      dst[0] = v.x; dst[1] = v.y; dst[2] = v.z; dst[3] = v.w;
    }
#pragma unroll
    for (int i = 0; i < 6; i++) {
      int flat4 = tid + i * 256;
      int row = flat4 >> 4, c4 = flat4 & 15;
      float4 v = *(const float4*)(Wlin + (size_t)row * NL + l0 + c4 * 4);
      float* dst = &wt[row * 65 + c4 * 4];
      dst[0] = v.x; dst[1] = v.y; dst[2] = v.z; dst[3] = v.w;
    }
    __syncthreads();
#pragma unroll 4
    for (int k = 0; k < 64; k++) {
      float yv[4], wv[6];
#pragma unroll
      for (int i = 0; i < 4; i++) yv[i] = yt[(f0 + i) * 65 + k];
#pragma unroll
      for (int j = 0; j < 6; j++) wv[j] = wt[(p0 + j) * 65 + k];
#pragma unroll
      for (int i = 0; i < 4; i++)
#pragma unroll
        for (int j = 0; j < 6; j++)
          acc[i][j] = fmaf(yv[i], wv[j], acc[i][j]);
    }
    __syncthreads();
  }
#pragma unroll
  for (int i = 0; i < 4; i++)
#pragma unroll
    for (int j = 0; j < 6; j++)
      atomicAdd(&out2[((size_t)(b * NP + p0 + j)) * NF + f0 + i], acc[i][j]);
}

// ---------------- K5: +blin, RevIN denorm, projector ----------------
__global__ __launch_bounds__(64) void k_final(
    const float* __restrict__ out2, const float* __restrict__ blin,
    const float* __restrict__ gamma, const float* __restrict__ beta,
    const float* __restrict__ wmean, const float* __restrict__ wstd,
    const float* __restrict__ Wp, const float* __restrict__ bp,
    float* __restrict__ out) {
  int b = blockIdx.x / NP;
  int p = blockIdx.x % NP;
  int f = threadIdx.x;
  float v = out2[((size_t)(b * NP + p)) * NF + f] + blin[p];
  v = (v - beta[f]) / gamma[f];
  v = v * wstd[b * NF + f] + wmean[b * NF + f];
  float s = v * Wp[f];
#pragma unroll
  for (int off = 32; off > 0; off >>= 1)
    s += __shfl_down(s, off, 64);
  if (f == 0) out[blockIdx.x] = s + bp[0];
}

extern "C" void kernel_launch(void* const* d_in, const int* in_sizes, int n_in,
                              void* d_out, int out_size, void* d_ws, size_t ws_size,
                              hipStream_t stream) {
  const float* x     = (const float*)d_in[0];
  const float* gamma = (const float*)d_in[1];
  const float* beta  = (const float*)d_in[2];
  const float* lnw   = (const float*)d_in[3];
  const float* lnb   = (const float*)d_in[4];
  const float* Wq    = (const float*)d_in[5];
  const float* bq    = (const float*)d_in[6];
  const float* Wk    = (const float*)d_in[7];
  const float* bk    = (const float*)d_in[8];
  const float* Wv    = (const float*)d_in[9];
  const float* bv    = (const float*)d_in[10];
  const float* Wo    = (const float*)d_in[11];
  const float* bo    = (const float*)d_in[12];
  const float* Wlin  = (const float*)d_in[13];
  const float* blin  = (const float*)d_in[14];
  const float* Wp    = (const float*)d_in[15];
  const float* bp    = (const float*)d_in[16];
  float* out = (float*)d_out;
  float* ws  = (float*)d_ws;

  float* wmean = ws + WS_MEAN;
  float* wstd  = ws + WS_STD;
  float* wrstd = ws + WS_RSTD;
  float* wKV   = ws + WS_KV;
  float* wZ    = ws + WS_Z;
  float* wout2 = ws + WS_OUT2;
  float* wyT   = ws + WS_YT;

  (void)hipMemsetAsync(wKV, 0, (size_t)(16384 + 2048 + 196608) * sizeof(float), stream);

  k_stats<<<NB * NF, 256, 0, stream>>>(x, wmean, wstd, wrstd);
  k_kv<<<NB * 64, 256, 0, stream>>>(x, gamma, beta, lnw, lnb, Wk, bk, Wv, bv,
                                    wmean, wrstd, wKV, wZ);
  k_qy<<<NB * 64, 256, 0, stream>>>(x, gamma, beta, lnw, lnb, Wq, bq, Wo, bo,
                                    wmean, wrstd, wKV, wZ, wyT);
  k_temporal<<<NB * SPLIT, 256, 0, stream>>>(wyT, Wlin, wout2);
  k_final<<<NB * NP, 64, 0, stream>>>(wout2, blin, gamma, beta, wmean, wstd, Wp, bp, out);
}

// Round 7
// 247.103 us; speedup vs baseline: 2.7502x; 1.2061x over previous
//
#include <hip/hip_runtime.h>
#include <cstddef>

#define NB 32
#define NF 64
#define NL 8192
#define NP 96
#define NH 8
#define TSPLIT 32

// ws layout in floats:
#define WS_MEAN 0           // 2048
#define WS_STD  2048        // 2048
#define WS_RSTD 4096        // 2048
#define WS_KV   6144        // NB*NH*64 = 16384
#define WS_Z    22528       // NB*NH*8  = 2048
#define WS_OUT2 24576       // NB*NP*NF = 196608
#define WS_WLB  221184      // NP*NL bf16 = 393216 floats
#define WS_YT   614400      // NB*NF*NL bf16 = 8388608 floats  (total ~36 MB)

typedef __bf16 bfx8 __attribute__((ext_vector_type(8)));
typedef float f32x4 __attribute__((ext_vector_type(4)));
#define MFMA16(a, b, c) __builtin_amdgcn_mfma_f32_16x16x32_bf16((a), (b), (c), 0, 0, 0)

// ---- bf16 helpers (RNE) ----
__device__ __forceinline__ unsigned short f2bf(float f) {
  unsigned u = __float_as_uint(f);
  unsigned r = u + 0x7FFFu + ((u >> 16) & 1u);
  return (unsigned short)(r >> 16);
}
__device__ __forceinline__ unsigned packbf2(float lo, float hi) {
  return (unsigned)f2bf(lo) | ((unsigned)f2bf(hi) << 16);
}
__device__ __forceinline__ float bflo(unsigned d) { return __uint_as_float(d << 16); }
__device__ __forceinline__ float bfhi(unsigned d) { return __uint_as_float(d & 0xFFFF0000u); }
__device__ __forceinline__ float bf1(unsigned short s) { return __uint_as_float(((unsigned)s) << 16); }

__device__ __forceinline__ bfx8 ldfrag(const unsigned short* p) {
  uint4 u = *(const uint4*)p;
  return __builtin_bit_cast(bfx8, u);
}

// ---------------- K1: RevIN stats per (b,f) ----------------
__global__ __launch_bounds__(256) void k_stats(const float* __restrict__ x,
                                               float* __restrict__ wmean,
                                               float* __restrict__ wstd,
                                               float* __restrict__ wrstd) {
  int bf = blockIdx.x;
  int tid = threadIdx.x;
  const float4* row4 = (const float4*)(x + (size_t)bf * NL);
  float s1 = 0.f, s2 = 0.f;
#pragma unroll
  for (int i = 0; i < NL / 4 / 256; i++) {
    float4 v = row4[tid + i * 256];
    s1 += v.x + v.y + v.z + v.w;
    s2 += v.x * v.x + v.y * v.y + v.z * v.z + v.w * v.w;
  }
  __shared__ float r1[256], r2[256];
  r1[tid] = s1; r2[tid] = s2;
  __syncthreads();
  for (int off = 128; off > 0; off >>= 1) {
    if (tid < off) { r1[tid] += r1[tid + off]; r2[tid] += r2[tid + off]; }
    __syncthreads();
  }
  if (tid == 0) {
    float m = r1[0] * (1.f / NL);
    float var = (r2[0] - (float)NL * m * m) * (1.f / (NL - 1));
    float sd = sqrtf(fmaxf(var, 0.f)) + 1e-5f;
    wmean[bf] = m;
    wstd[bf] = sd;
    wrstd[bf] = 1.f / sd;
  }
}

// ---------------- K1b: Wlin fp32 -> bf16 ----------------
__global__ __launch_bounds__(256) void k_wlb(const float* __restrict__ Wlin,
                                             unsigned short* __restrict__ wlb) {
  int i = blockIdx.x * 256 + threadIdx.x;   // over NP*NL/4 float4 groups
  float4 v = ((const float4*)Wlin)[i];
  uint2 o; o.x = packbf2(v.x, v.y); o.y = packbf2(v.z, v.w);
  *(uint2*)&wlb[i * 4] = o;
}

// ---------------- K2: K/V projection (MFMA) + KV,Z accumulation (MFMA) ----------------
// 256 threads, 128 l per block, grid NB*64.  LDS 40960 B -> 4 blocks/CU.
__global__ __launch_bounds__(256, 4) void k_kv(
    const float* __restrict__ x,
    const float* __restrict__ gamma, const float* __restrict__ beta,
    const float* __restrict__ lnw, const float* __restrict__ lnb,
    const float* __restrict__ Wk, const float* __restrict__ bk,
    const float* __restrict__ Wv, const float* __restrict__ bv,
    const float* __restrict__ wmean, const float* __restrict__ wrstd,
    float* __restrict__ wKV, float* __restrict__ wZ) {
  __shared__ __align__(16) char smem[40960];
  unsigned short* hA  = (unsigned short*)smem;            // [128][72] xn bf16
  unsigned short* WkB = (unsigned short*)(smem + 18432);  // [64 j][72 f] folded
  unsigned short* WvB = (unsigned short*)(smem + 27648);  // [64 j][72 f] folded
  unsigned short* pK  = (unsigned short*)smem;            // overlay: [64 j][136 l]
  unsigned short* pV  = (unsigned short*)(smem + 17408);  // overlay: [64 j][136 l]
  float* SkT   = (float*)(smem + 36864);  // [256] Sk|Tk|Sv|Tv
  float* Tpart = (float*)(smem + 37888);  // [2][4][64]
  float* mun   = (float*)(smem + 39936);  // [128]
  float* rsn   = (float*)(smem + 40448);  // [128]

  const int tid = threadIdx.x;
  const int b = blockIdx.x >> 6;
  const int L0 = (blockIdx.x & 63) * 128;
  const int lane = tid & 63, wv = tid >> 6;
  const int mm = lane & 15, qd = lane >> 4;

  // ---- phase 0: stage Wk/Wv rows (lnw-folded bf16) + T partials (coalesced) ----
  {
    int jj = tid >> 2, g = tid & 3;      // row j, f-quarter
    int f0 = g * 16;
    float tkp = 0.f, tvp = 0.f;
#pragma unroll
    for (int i = 0; i < 4; i++) {
      int f = f0 + i * 4;
      float4 wk4 = *(const float4*)&Wk[jj * NF + f];
      float4 wv4 = *(const float4*)&Wv[jj * NF + f];
      float4 lw  = *(const float4*)&lnw[f];
      float4 lb  = *(const float4*)&lnb[f];
      uint2 pk2, pv2;
      pk2.x = packbf2(wk4.x * lw.x, wk4.y * lw.y);
      pk2.y = packbf2(wk4.z * lw.z, wk4.w * lw.w);
      pv2.x = packbf2(wv4.x * lw.x, wv4.y * lw.y);
      pv2.y = packbf2(wv4.z * lw.z, wv4.w * lw.w);
      *(uint2*)&WkB[jj * 72 + f] = pk2;
      *(uint2*)&WvB[jj * 72 + f] = pv2;
      tkp += lb.x * wk4.x + lb.y * wk4.y + lb.z * wk4.z + lb.w * wk4.w;
      tvp += lb.x * wv4.x + lb.y * wv4.y + lb.z * wv4.z + lb.w * wv4.w;
    }
    Tpart[g * 64 + jj] = tkp;
    Tpart[256 + g * 64 + jj] = tvp;
  }

  // ---- phase 1: xn (RevIN affine), LN stats, row-major bf16 pack ----
  if (tid < 128) {
    float xn[NF];
    float mu = 0.f;
#pragma unroll
    for (int f = 0; f < NF; f++) {
      float v = x[((size_t)(b * NF + f)) * NL + L0 + tid];
      v = (v - wmean[b * NF + f]) * wrstd[b * NF + f] * gamma[f] + beta[f];
      xn[f] = v; mu += v;
    }
    mu *= (1.f / NF);
    float var = 0.f;
#pragma unroll
    for (int f = 0; f < NF; f++) { float d = xn[f] - mu; var += d * d; }
    float rs = rsqrtf(var * (1.f / NF) + 1e-5f);
    mun[tid] = mu; rsn[tid] = rs;
    unsigned* hrow = (unsigned*)&hA[tid * 72];
#pragma unroll
    for (int f2 = 0; f2 < 32; f2++)
      hrow[f2] = packbf2(xn[2 * f2], xn[2 * f2 + 1]);
  }
  __syncthreads();

  // ---- S (sum of folded bf16 row) and T (+bias) finalize ----
  if (tid < 128) {
    int sel = tid >> 6, j = tid & 63;
    const unsigned* wr = (const unsigned*)((sel ? WvB : WkB) + j * 72);
    float s = 0.f;
#pragma unroll
    for (int i = 0; i < 32; i++) { unsigned d = wr[i]; s += bflo(d) + bfhi(d); }
    float t = Tpart[sel * 256 + j] + Tpart[sel * 256 + 64 + j] +
              Tpart[sel * 256 + 128 + j] + Tpart[sel * 256 + 192 + j];
    t += sel ? bv[j] : bk[j];
    SkT[sel * 128 + j] = s;
    SkT[sel * 128 + 64 + j] = t;
  }
  __syncthreads();

  // ---- projection MFMA: out[l][j], wave handles 32 l x 64 j ----
  const f32x4 fz = {0.f, 0.f, 0.f, 0.f};
  f32x4 kacc[2][4], vacc[2][4];
#pragma unroll
  for (int i = 0; i < 2; i++)
#pragma unroll
    for (int jt = 0; jt < 4; jt++) { kacc[i][jt] = fz; vacc[i][jt] = fz; }

#pragma unroll
  for (int kc = 0; kc < 2; kc++) {
    bfx8 a0 = ldfrag(&hA[(wv * 32 + mm) * 72 + kc * 32 + qd * 8]);
    bfx8 a1 = ldfrag(&hA[(wv * 32 + 16 + mm) * 72 + kc * 32 + qd * 8]);
#pragma unroll
    for (int jt = 0; jt < 4; jt++) {
      bfx8 bkf = ldfrag(&WkB[(jt * 16 + mm) * 72 + kc * 32 + qd * 8]);
      bfx8 bvf = ldfrag(&WvB[(jt * 16 + mm) * 72 + kc * 32 + qd * 8]);
      kacc[0][jt] = MFMA16(a0, bkf, kacc[0][jt]);
      kacc[1][jt] = MFMA16(a1, bkf, kacc[1][jt]);
      vacc[0][jt] = MFMA16(a0, bvf, vacc[0][jt]);
      vacc[1][jt] = MFMA16(a1, bvf, vacc[1][jt]);
    }
  }

  // ---- postfix: K = rs*(raw - mu*Sk) + Tk -> phi;  V likewise (no phi) ----
#pragma unroll
  for (int lt2 = 0; lt2 < 2; lt2++) {
    float4 mu4 = *(const float4*)&mun[wv * 32 + lt2 * 16 + qd * 4];
    float4 rs4 = *(const float4*)&rsn[wv * 32 + lt2 * 16 + qd * 4];
    float muv[4] = {mu4.x, mu4.y, mu4.z, mu4.w};
    float rsv[4] = {rs4.x, rs4.y, rs4.z, rs4.w};
#pragma unroll
    for (int jt = 0; jt < 4; jt++) {
      int j = jt * 16 + mm;
      float Sk = SkT[j], Tk = SkT[64 + j], Sv = SkT[128 + j], Tv = SkT[192 + j];
#pragma unroll
      for (int r = 0; r < 4; r++) {
        float kk = rsv[r] * (kacc[lt2][jt][r] - muv[r] * Sk) + Tk;
        kacc[lt2][jt][r] = (kk > 0.f) ? (kk + 1.f) : __expf(kk);
        vacc[lt2][jt][r] = rsv[r] * (vacc[lt2][jt][r] - muv[r] * Sv) + Tv;
      }
    }
  }
  __syncthreads();   // hA/WkB/WvB dead -> overlay with pK/pV

  // ---- pack phi(K), V into [64 j][136 l] bf16 ----
#pragma unroll
  for (int lt2 = 0; lt2 < 2; lt2++) {
    int l0 = wv * 32 + lt2 * 16 + qd * 4;
#pragma unroll
    for (int jt = 0; jt < 4; jt++) {
      int j = jt * 16 + mm;
      uint2 dk, dv;
      dk.x = packbf2(kacc[lt2][jt][0], kacc[lt2][jt][1]);
      dk.y = packbf2(kacc[lt2][jt][2], kacc[lt2][jt][3]);
      dv.x = packbf2(vacc[lt2][jt][0], vacc[lt2][jt][1]);
      dv.y = packbf2(vacc[lt2][jt][2], vacc[lt2][jt][3]);
      *(uint2*)&pK[j * 136 + l0] = dk;
      *(uint2*)&pV[j * 136 + l0] = dv;
    }
  }
  __syncthreads();

  // ---- KV reduction MFMA: wave = head pair {2wv, 2wv+1}; A=phi(K)^T, B=V ----
  {
    f32x4 racc = fz;
#pragma unroll
    for (int kb = 0; kb < 4; kb++) {
      bfx8 ak = ldfrag(&pK[(wv * 16 + mm) * 136 + kb * 32 + qd * 8]);
      bfx8 bv8 = ldfrag(&pV[(wv * 16 + mm) * 136 + kb * 32 + qd * 8]);
      racc = MFMA16(ak, bv8, racc);
    }
    int eh = mm >> 3, e = mm & 7;
#pragma unroll
    for (int r = 0; r < 4; r++) {
      int row = qd * 4 + r;
      if ((row >> 3) == eh)
        atomicAdd(&wKV[(b * NH + wv * 2 + eh) * 64 + (row & 7) * 8 + e], racc[r]);
    }
  }
  // ---- Z: row sums of pK ----
  if (tid < 64) {
    const unsigned* kr = (const unsigned*)&pK[tid * 136];
    float zs = 0.f;
#pragma unroll
    for (int i = 0; i < 64; i++) { unsigned d = kr[i]; zs += bflo(d) + bfhi(d); }
    atomicAdd(&wZ[b * 64 + tid], zs);
  }
}

// ---------------- K3: Q MFMA + readout (in-place LDS) + O MFMA + residual -> yT bf16 ----------------
// 256 threads, 128 l, grid NB*64.  LDS 60160 B -> 2 blocks/CU.
__global__ __launch_bounds__(256, 2) void k_qy(
    const float* __restrict__ x,
    const float* __restrict__ gamma, const float* __restrict__ beta,
    const float* __restrict__ lnw, const float* __restrict__ lnb,
    const float* __restrict__ Wq, const float* __restrict__ bq,
    const float* __restrict__ Wo, const float* __restrict__ bo,
    const float* __restrict__ wmean, const float* __restrict__ wrstd,
    const float* __restrict__ wKV, const float* __restrict__ wZ,
    unsigned short* __restrict__ yTb) {
  __shared__ __align__(16) char smem[60160];
  unsigned short* hA  = (unsigned short*)smem;             // [128][72] xn bf16
  unsigned short* WqB = (unsigned short*)(smem + 18432);   // [64 j][72 f] folded
  unsigned short* WoB = (unsigned short*)(smem + 27648);   // [64 f][72 e]
  unsigned short* qaA = (unsigned short*)(smem + 36864);   // [128 l][72] phi(Q) -> att
  float* kvz   = (float*)(smem + 55296);  // [576]
  float* mun   = (float*)(smem + 57600);
  float* rsn   = (float*)(smem + 58112);
  float* SqTq  = (float*)(smem + 58624);  // [128]
  float* Tpart = (float*)(smem + 59136);  // [4][64]

  const int tid = threadIdx.x;
  const int b = blockIdx.x >> 6;
  const int L0 = (blockIdx.x & 63) * 128;
  const int lane = tid & 63, wv = tid >> 6;
  const int mm = lane & 15, qd = lane >> 4;

  // ---- phase 0: stage Wq (folded) + Wo rows + kvz ----
  {
    int jj = tid >> 2, g = tid & 3;
    int f0 = g * 16;
    float tqp = 0.f;
#pragma unroll
    for (int i = 0; i < 4; i++) {
      int f = f0 + i * 4;
      float4 wq4 = *(const float4*)&Wq[jj * NF + f];
      float4 wo4 = *(const float4*)&Wo[jj * NF + f];
      float4 lw  = *(const float4*)&lnw[f];
      float4 lb  = *(const float4*)&lnb[f];
      uint2 pq2, po2;
      pq2.x = packbf2(wq4.x * lw.x, wq4.y * lw.y);
      pq2.y = packbf2(wq4.z * lw.z, wq4.w * lw.w);
      po2.x = packbf2(wo4.x, wo4.y);
      po2.y = packbf2(wo4.z, wo4.w);
      *(uint2*)&WqB[jj * 72 + f] = pq2;
      *(uint2*)&WoB[jj * 72 + f] = po2;
      tqp += lb.x * wq4.x + lb.y * wq4.y + lb.z * wq4.z + lb.w * wq4.w;
    }
    Tpart[g * 64 + jj] = tqp;
  }
  for (int i = tid; i < 576; i += 256)
    kvz[i] = (i < 512) ? wKV[b * 512 + i] : wZ[b * 64 + i - 512];

  // ---- phase 1: xn ----
  if (tid < 128) {
    float xn[NF];
    float mu = 0.f;
#pragma unroll
    for (int f = 0; f < NF; f++) {
      float v = x[((size_t)(b * NF + f)) * NL + L0 + tid];
      v = (v - wmean[b * NF + f]) * wrstd[b * NF + f] * gamma[f] + beta[f];
      xn[f] = v; mu += v;
    }
    mu *= (1.f / NF);
    float var = 0.f;
#pragma unroll
    for (int f = 0; f < NF; f++) { float d = xn[f] - mu; var += d * d; }
    float rs = rsqrtf(var * (1.f / NF) + 1e-5f);
    mun[tid] = mu; rsn[tid] = rs;
    unsigned* hrow = (unsigned*)&hA[tid * 72];
#pragma unroll
    for (int f2 = 0; f2 < 32; f2++)
      hrow[f2] = packbf2(xn[2 * f2], xn[2 * f2 + 1]);
  }
  __syncthreads();

  if (tid < 64) {
    const unsigned* wr = (const unsigned*)(WqB + tid * 72);
    float s = 0.f;
#pragma unroll
    for (int i = 0; i < 32; i++) { unsigned d = wr[i]; s += bflo(d) + bfhi(d); }
    float t = Tpart[tid] + Tpart[64 + tid] + Tpart[128 + tid] + Tpart[192 + tid] + bq[tid];
    SqTq[tid] = s; SqTq[64 + tid] = t;
  }
  __syncthreads();

  const f32x4 fz = {0.f, 0.f, 0.f, 0.f};

  // ---- Q-MFMA ----
  {
    f32x4 qacc[2][4];
#pragma unroll
    for (int i = 0; i < 2; i++)
#pragma unroll
      for (int jt = 0; jt < 4; jt++) qacc[i][jt] = fz;
#pragma unroll
    for (int kc = 0; kc < 2; kc++) {
      bfx8 a0 = ldfrag(&hA[(wv * 32 + mm) * 72 + kc * 32 + qd * 8]);
      bfx8 a1 = ldfrag(&hA[(wv * 32 + 16 + mm) * 72 + kc * 32 + qd * 8]);
#pragma unroll
      for (int jt = 0; jt < 4; jt++) {
        bfx8 bqf = ldfrag(&WqB[(jt * 16 + mm) * 72 + kc * 32 + qd * 8]);
        qacc[0][jt] = MFMA16(a0, bqf, qacc[0][jt]);
        qacc[1][jt] = MFMA16(a1, bqf, qacc[1][jt]);
      }
    }
    // postfix + phi, scatter to qaA rows [l][j]
#pragma unroll
    for (int lt2 = 0; lt2 < 2; lt2++) {
      float4 mu4 = *(const float4*)&mun[wv * 32 + lt2 * 16 + qd * 4];
      float4 rs4 = *(const float4*)&rsn[wv * 32 + lt2 * 16 + qd * 4];
      float muv[4] = {mu4.x, mu4.y, mu4.z, mu4.w};
      float rsv[4] = {rs4.x, rs4.y, rs4.z, rs4.w};
      int l0 = wv * 32 + lt2 * 16 + qd * 4;
#pragma unroll
      for (int jt = 0; jt < 4; jt++) {
        int j = jt * 16 + mm;
        float Sj = SqTq[j], Tj = SqTq[64 + j];
#pragma unroll
        for (int r = 0; r < 4; r++) {
          float q = rsv[r] * (qacc[lt2][jt][r] - muv[r] * Sj) + Tj;
          q = (q > 0.f) ? (q + 1.f) : __expf(q);
          qaA[(l0 + r) * 72 + j] = f2bf(q);
        }
      }
    }
  }
  __syncthreads();

  // ---- readout in place: thread = (4 l, 1 head) tile of qaA ----
  {
    int lt = tid & 31, hd = tid >> 5;
    int lbase = lt * 4;
    float qv[4][8];
#pragma unroll
    for (int i = 0; i < 4; i++) {
      uint4 u = *(const uint4*)&qaA[(lbase + i) * 72 + hd * 8];
      qv[i][0] = bflo(u.x); qv[i][1] = bfhi(u.x);
      qv[i][2] = bflo(u.y); qv[i][3] = bfhi(u.y);
      qv[i][4] = bflo(u.z); qv[i][5] = bfhi(u.z);
      qv[i][6] = bflo(u.w); qv[i][7] = bfhi(u.w);
    }
    float att[4][8], nrm[4];
#pragma unroll
    for (int i = 0; i < 4; i++) {
      nrm[i] = 1e-6f;
#pragma unroll
      for (int e = 0; e < 8; e++) att[i][e] = 0.f;
    }
#pragma unroll
    for (int d = 0; d < 8; d++) {
      float zd = kvz[512 + hd * 8 + d];
      float4 kva = *(const float4*)&kvz[hd * 64 + d * 8];
      float4 kvb = *(const float4*)&kvz[hd * 64 + d * 8 + 4];
#pragma unroll
      for (int i = 0; i < 4; i++) {
        float qq = qv[i][d];
        nrm[i] = fmaf(qq, zd, nrm[i]);
        att[i][0] = fmaf(qq, kva.x, att[i][0]);
        att[i][1] = fmaf(qq, kva.y, att[i][1]);
        att[i][2] = fmaf(qq, kva.z, att[i][2]);
        att[i][3] = fmaf(qq, kva.w, att[i][3]);
        att[i][4] = fmaf(qq, kvb.x, att[i][4]);
        att[i][5] = fmaf(qq, kvb.y, att[i][5]);
        att[i][6] = fmaf(qq, kvb.z, att[i][6]);
        att[i][7] = fmaf(qq, kvb.w, att[i][7]);
      }
    }
#pragma unroll
    for (int i = 0; i < 4; i++) {
      float inv = 1.f / nrm[i];
      uint4 o;
      o.x = packbf2(att[i][0] * inv, att[i][1] * inv);
      o.y = packbf2(att[i][2] * inv, att[i][3] * inv);
      o.z = packbf2(att[i][4] * inv, att[i][5] * inv);
      o.w = packbf2(att[i][6] * inv, att[i][7] * inv);
      *(uint4*)&qaA[(lbase + i) * 72 + hd * 8] = o;
    }
  }
  __syncthreads();

  // ---- O-MFMA: y[l][f] = att[l][e] . Wo[f][e] ----
  {
    f32x4 yacc[2][4];
#pragma unroll
    for (int i = 0; i < 2; i++)
#pragma unroll
      for (int ft = 0; ft < 4; ft++) yacc[i][ft] = fz;
#pragma unroll
    for (int ec = 0; ec < 2; ec++) {
      bfx8 a0 = ldfrag(&qaA[(wv * 32 + mm) * 72 + ec * 32 + qd * 8]);
      bfx8 a1 = ldfrag(&qaA[(wv * 32 + 16 + mm) * 72 + ec * 32 + qd * 8]);
#pragma unroll
      for (int ft = 0; ft < 4; ft++) {
        bfx8 bof = ldfrag(&WoB[(ft * 16 + mm) * 72 + ec * 32 + qd * 8]);
        yacc[0][ft] = MFMA16(a0, bof, yacc[0][ft]);
        yacc[1][ft] = MFMA16(a1, bof, yacc[1][ft]);
      }
    }
    // epilogue: + xn residual + bo -> yT bf16 (B,F,L)
#pragma unroll
    for (int lt2 = 0; lt2 < 2; lt2++) {
      int l0 = wv * 32 + lt2 * 16 + qd * 4;
#pragma unroll
      for (int ft = 0; ft < 4; ft++) {
        int ff = ft * 16 + mm;
        float bof = bo[ff];
        float v0 = yacc[lt2][ft][0] + bf1(hA[(l0 + 0) * 72 + ff]) + bof;
        float v1 = yacc[lt2][ft][1] + bf1(hA[(l0 + 1) * 72 + ff]) + bof;
        float v2 = yacc[lt2][ft][2] + bf1(hA[(l0 + 2) * 72 + ff]) + bof;
        float v3 = yacc[lt2][ft][3] + bf1(hA[(l0 + 3) * 72 + ff]) + bof;
        uint2 o2;
        o2.x = packbf2(v0, v1);
        o2.y = packbf2(v2, v3);
        *(uint2*)&yTb[((size_t)(b * NF + ff)) * NL + L0 + l0] = o2;
      }
    }
  }
}

// ---------------- K4: temporal GEMM via MFMA, no LDS ----------------
// out2[b,p,f] += sum_l Wlin[p,l]*y[b,f,l]
// A-rows = wlb[p][l], B-rows = yTb[f][l]; C col=f (lane&15), row=p (quad*4+r).
// grid NB*TSPLIT blocks; wave wv owns f-tile wv, 6 p-tiles of 16.
__global__ __launch_bounds__(256) void k_temporal(
    const unsigned short* __restrict__ yTb, const unsigned short* __restrict__ wlb,
    float* __restrict__ out2) {
  const int tid = threadIdx.x, lane = tid & 63, wvx = tid >> 6;
  const int mm = lane & 15, qd = lane >> 4;
  const int b = blockIdx.x / TSPLIT;
  const int kc = blockIdx.x % TSPLIT;
  const int Lc = NL / TSPLIT;    // 256
  const unsigned short* yrow = yTb + ((size_t)(b * NF + wvx * 16 + mm)) * NL + kc * Lc + qd * 8;
  const unsigned short* wrow = wlb + (size_t)mm * NL + kc * Lc + qd * 8;
  const f32x4 fz = {0.f, 0.f, 0.f, 0.f};
  f32x4 acc[6];
#pragma unroll
  for (int pt = 0; pt < 6; pt++) acc[pt] = fz;

#pragma unroll 2
  for (int ks = 0; ks < Lc / 32; ks++) {
    bfx8 bfr = ldfrag(yrow + ks * 32);
#pragma unroll
    for (int pt = 0; pt < 6; pt++) {
      bfx8 afr = ldfrag(wrow + (size_t)(pt * 16) * NL + ks * 32);
      acc[pt] = MFMA16(afr, bfr, acc[pt]);
    }
  }
  const int ff = wvx * 16 + mm;
#pragma unroll
  for (int pt = 0; pt < 6; pt++) {
#pragma unroll
    for (int r = 0; r < 4; r++) {
      int p = pt * 16 + qd * 4 + r;
      atomicAdd(&out2[((size_t)(b * NP + p)) * NF + ff], acc[pt][r]);
    }
  }
}

// ---------------- K5: +blin, RevIN denorm, projector ----------------
__global__ __launch_bounds__(64) void k_final(
    const float* __restrict__ out2, const float* __restrict__ blin,
    const float* __restrict__ gamma, const float* __restrict__ beta,
    const float* __restrict__ wmean, const float* __restrict__ wstd,
    const float* __restrict__ Wp, const float* __restrict__ bp,
    float* __restrict__ out) {
  int b = blockIdx.x / NP;
  int p = blockIdx.x % NP;
  int f = threadIdx.x;
  float v = out2[((size_t)(b * NP + p)) * NF + f] + blin[p];
  v = (v - beta[f]) / gamma[f];
  v = v * wstd[b * NF + f] + wmean[b * NF + f];
  float s = v * Wp[f];
#pragma unroll
  for (int off = 32; off > 0; off >>= 1)
    s += __shfl_down(s, off, 64);
  if (f == 0) out[blockIdx.x] = s + bp[0];
}

extern "C" void kernel_launch(void* const* d_in, const int* in_sizes, int n_in,
                              void* d_out, int out_size, void* d_ws, size_t ws_size,
                              hipStream_t stream) {
  const float* x     = (const float*)d_in[0];
  const float* gamma = (const float*)d_in[1];
  const float* beta  = (const float*)d_in[2];
  const float* lnw   = (const float*)d_in[3];
  const float* lnb   = (const float*)d_in[4];
  const float* Wq    = (const float*)d_in[5];
  const float* bq    = (const float*)d_in[6];
  const float* Wk    = (const float*)d_in[7];
  const float* bk    = (const float*)d_in[8];
  const float* Wv    = (const float*)d_in[9];
  const float* bv    = (const float*)d_in[10];
  const float* Wo    = (const float*)d_in[11];
  const float* bo    = (const float*)d_in[12];
  const float* Wlin  = (const float*)d_in[13];
  const float* blin  = (const float*)d_in[14];
  const float* Wp    = (const float*)d_in[15];
  const float* bp    = (const float*)d_in[16];
  float* out = (float*)d_out;
  float* ws  = (float*)d_ws;

  float* wmean = ws + WS_MEAN;
  float* wstd  = ws + WS_STD;
  float* wrstd = ws + WS_RSTD;
  float* wKV   = ws + WS_KV;
  float* wZ    = ws + WS_Z;
  float* wout2 = ws + WS_OUT2;
  unsigned short* wlb = (unsigned short*)(ws + WS_WLB);
  unsigned short* yTb = (unsigned short*)(ws + WS_YT);

  (void)hipMemsetAsync(wKV, 0, (size_t)(16384 + 2048 + 196608) * sizeof(float), stream);

  k_stats<<<NB * NF, 256, 0, stream>>>(x, wmean, wstd, wrstd);
  k_wlb<<<NP * NL / 4 / 256, 256, 0, stream>>>(Wlin, wlb);
  k_kv<<<NB * 64, 256, 0, stream>>>(x, gamma, beta, lnw, lnb, Wk, bk, Wv, bv,
                                    wmean, wrstd, wKV, wZ);
  k_qy<<<NB * 64, 256, 0, stream>>>(x, gamma, beta, lnw, lnb, Wq, bq, Wo, bo,
                                    wmean, wrstd, wKV, wZ, yTb);
  k_temporal<<<NB * TSPLIT, 256, 0, stream>>>(yTb, wlb, wout2);
  k_final<<<NB * NP, 64, 0, stream>>>(wout2, blin, gamma, beta, wmean, wstd, Wp, bp, out);
}

// Round 8
// 233.905 us; speedup vs baseline: 2.9054x; 1.0564x over previous
//
#include <hip/hip_runtime.h>
#include <cstddef>

#define NB 32
#define NF 64
#define NL 8192
#define NP 96
#define NH 8
#define TSPLIT 32

// ws layout in floats:
#define WS_MEAN 0           // 2048
#define WS_STD  2048        // 2048
#define WS_RSTD 4096        // 2048
#define WS_KV   6144        // NB*NH*64 = 16384
#define WS_Z    22528       // NB*NH*8  = 2048
#define WS_OUT2 24576       // NB*NP*NF = 196608 -> ends 221184
#define WS_MUN  221184      // NB*NL = 262144
#define WS_RSN  483328      // NB*NL = 262144
#define WS_WLB  745472      // NP*NL bf16 = 393216 floats
#define WS_XNB  1138688     // NB*NF*NL bf16 = 8388608 floats
#define WS_YT   9527296     // NB*NF*NL bf16 = 8388608 floats (total ~72 MB)

typedef __bf16 bfx8 __attribute__((ext_vector_type(8)));
typedef float f32x4 __attribute__((ext_vector_type(4)));
#define MFMA16(a, b, c) __builtin_amdgcn_mfma_f32_16x16x32_bf16((a), (b), (c), 0, 0, 0)

// ---- bf16 helpers (RNE) ----
__device__ __forceinline__ unsigned short f2bf(float f) {
  unsigned u = __float_as_uint(f);
  unsigned r = u + 0x7FFFu + ((u >> 16) & 1u);
  return (unsigned short)(r >> 16);
}
__device__ __forceinline__ unsigned packbf2(float lo, float hi) {
  return (unsigned)f2bf(lo) | ((unsigned)f2bf(hi) << 16);
}
__device__ __forceinline__ float bflo(unsigned d) { return __uint_as_float(d << 16); }
__device__ __forceinline__ float bfhi(unsigned d) { return __uint_as_float(d & 0xFFFF0000u); }
__device__ __forceinline__ float bf1(unsigned short s) { return __uint_as_float(((unsigned)s) << 16); }

__device__ __forceinline__ bfx8 ldfrag(const unsigned short* p) {
  uint4 u = *(const uint4*)p;
  return __builtin_bit_cast(bfx8, u);
}

// ---------------- K1: RevIN stats per (b,f) ----------------
__global__ __launch_bounds__(256) void k_stats(const float* __restrict__ x,
                                               float* __restrict__ wmean,
                                               float* __restrict__ wstd,
                                               float* __restrict__ wrstd) {
  int bf = blockIdx.x;
  int tid = threadIdx.x;
  const float4* row4 = (const float4*)(x + (size_t)bf * NL);
  float s1 = 0.f, s2 = 0.f;
#pragma unroll
  for (int i = 0; i < NL / 4 / 256; i++) {
    float4 v = row4[tid + i * 256];
    s1 += v.x + v.y + v.z + v.w;
    s2 += v.x * v.x + v.y * v.y + v.z * v.z + v.w * v.w;
  }
  __shared__ float r1[256], r2[256];
  r1[tid] = s1; r2[tid] = s2;
  __syncthreads();
  for (int off = 128; off > 0; off >>= 1) {
    if (tid < off) { r1[tid] += r1[tid + off]; r2[tid] += r2[tid + off]; }
    __syncthreads();
  }
  if (tid == 0) {
    float m = r1[0] * (1.f / NL);
    float var = (r2[0] - (float)NL * m * m) * (1.f / (NL - 1));
    float sd = sqrtf(fmaxf(var, 0.f)) + 1e-5f;
    wmean[bf] = m;
    wstd[bf] = sd;
    wrstd[bf] = 1.f / sd;
  }
}

// ---------------- K1b: Wlin fp32 -> bf16 tiled [l/32][96 p][32 l] ----------------
__global__ __launch_bounds__(256) void k_wlb(const float* __restrict__ Wlin,
                                             unsigned short* __restrict__ wlb) {
  int i = blockIdx.x * 256 + threadIdx.x;   // NP*NL/8 threads
  int p = i >> 10;                          // NL/8 = 1024
  int l8 = (i & 1023) * 8;
  float4 va = *(const float4*)&Wlin[(size_t)p * NL + l8];
  float4 vb = *(const float4*)&Wlin[(size_t)p * NL + l8 + 4];
  uint4 o;
  o.x = packbf2(va.x, va.y); o.y = packbf2(va.z, va.w);
  o.z = packbf2(vb.x, vb.y); o.w = packbf2(vb.z, vb.w);
  *(uint4*)&wlb[(((size_t)(l8 >> 5)) * NP + p) * 32 + (l8 & 31)] = o;
}

// ---------------- K2: K/V projection (MFMA) + KV,Z accumulation + xn export ----------------
// 256 threads, 128 l per block, grid NB*64.  LDS 40960 B -> 4 blocks/CU.
__global__ __launch_bounds__(256, 4) void k_kv(
    const float* __restrict__ x,
    const float* __restrict__ gamma, const float* __restrict__ beta,
    const float* __restrict__ lnw, const float* __restrict__ lnb,
    const float* __restrict__ Wk, const float* __restrict__ bk,
    const float* __restrict__ Wv, const float* __restrict__ bv,
    const float* __restrict__ wmean, const float* __restrict__ wrstd,
    float* __restrict__ wKV, float* __restrict__ wZ,
    float* __restrict__ wmun, float* __restrict__ wrsn,
    unsigned short* __restrict__ xnb) {
  __shared__ __align__(16) char smem[40960];
  unsigned short* hA  = (unsigned short*)smem;            // [128][72] xn bf16
  unsigned short* WkB = (unsigned short*)(smem + 18432);  // [64 j][72 f] folded
  unsigned short* WvB = (unsigned short*)(smem + 27648);  // [64 j][72 f] folded
  unsigned short* pK  = (unsigned short*)smem;            // overlay: [64 j][136 l]
  unsigned short* pV  = (unsigned short*)(smem + 17408);  // overlay: [64 j][136 l]
  float* SkT   = (float*)(smem + 36864);  // [256] Sk|Tk|Sv|Tv
  float* Tpart = (float*)(smem + 37888);  // [2][4][64]
  float* mun   = (float*)(smem + 39936);  // [128]
  float* rsn   = (float*)(smem + 40448);  // [128]

  const int tid = threadIdx.x;
  const int b = blockIdx.x >> 6;
  const int tI = blockIdx.x & 63;
  const int L0 = tI * 128;
  const int lane = tid & 63, wv = tid >> 6;
  const int mm = lane & 15, qd = lane >> 4;

  // ---- phase 0: stage Wk/Wv rows (lnw-folded bf16) + T partials ----
  {
    int jj = tid >> 2, g = tid & 3;
    int f0 = g * 16;
    float tkp = 0.f, tvp = 0.f;
#pragma unroll
    for (int i = 0; i < 4; i++) {
      int f = f0 + i * 4;
      float4 wk4 = *(const float4*)&Wk[jj * NF + f];
      float4 wv4 = *(const float4*)&Wv[jj * NF + f];
      float4 lw  = *(const float4*)&lnw[f];
      float4 lb  = *(const float4*)&lnb[f];
      uint2 pk2, pv2;
      pk2.x = packbf2(wk4.x * lw.x, wk4.y * lw.y);
      pk2.y = packbf2(wk4.z * lw.z, wk4.w * lw.w);
      pv2.x = packbf2(wv4.x * lw.x, wv4.y * lw.y);
      pv2.y = packbf2(wv4.z * lw.z, wv4.w * lw.w);
      *(uint2*)&WkB[jj * 72 + f] = pk2;
      *(uint2*)&WvB[jj * 72 + f] = pv2;
      tkp += lb.x * wk4.x + lb.y * wk4.y + lb.z * wk4.z + lb.w * wk4.w;
      tvp += lb.x * wv4.x + lb.y * wv4.y + lb.z * wv4.z + lb.w * wv4.w;
    }
    Tpart[g * 64 + jj] = tkp;
    Tpart[256 + g * 64 + jj] = tvp;
  }

  // ---- phase 1: xn (RevIN affine), LN stats, pack to LDS; export mu/rs ----
  if (tid < 128) {
    float xn[NF];
    float mu = 0.f;
#pragma unroll
    for (int f = 0; f < NF; f++) {
      float v = x[((size_t)(b * NF + f)) * NL + L0 + tid];
      v = (v - wmean[b * NF + f]) * wrstd[b * NF + f] * gamma[f] + beta[f];
      xn[f] = v; mu += v;
    }
    mu *= (1.f / NF);
    float var = 0.f;
#pragma unroll
    for (int f = 0; f < NF; f++) { float d = xn[f] - mu; var += d * d; }
    float rs = rsqrtf(var * (1.f / NF) + 1e-5f);
    mun[tid] = mu; rsn[tid] = rs;
    wmun[(size_t)b * NL + L0 + tid] = mu;
    wrsn[(size_t)b * NL + L0 + tid] = rs;
    unsigned* hrow = (unsigned*)&hA[tid * 72];
#pragma unroll
    for (int f2 = 0; f2 < 32; f2++)
      hrow[f2] = packbf2(xn[2 * f2], xn[2 * f2 + 1]);
  }
  __syncthreads();

  // ---- export xn tile to global (LDS-image order [l][f]) ----
  {
    int row = tid >> 1, half = tid & 1;
    const uint4* s4 = (const uint4*)&hA[row * 72 + half * 32];
    uint4* d4 = (uint4*)(xnb + (((size_t)(b * 64 + tI) * 128 + row) * 64 + half * 32));
    d4[0] = s4[0]; d4[1] = s4[1]; d4[2] = s4[2]; d4[3] = s4[3];
  }

  // ---- S (sum of folded bf16 row) and T (+bias) finalize ----
  if (tid < 128) {
    int sel = tid >> 6, j = tid & 63;
    const unsigned* wr = (const unsigned*)((sel ? WvB : WkB) + j * 72);
    float s = 0.f;
#pragma unroll
    for (int i = 0; i < 32; i++) { unsigned d = wr[i]; s += bflo(d) + bfhi(d); }
    float t = Tpart[sel * 256 + j] + Tpart[sel * 256 + 64 + j] +
              Tpart[sel * 256 + 128 + j] + Tpart[sel * 256 + 192 + j];
    t += sel ? bv[j] : bk[j];
    SkT[sel * 128 + j] = s;
    SkT[sel * 128 + 64 + j] = t;
  }
  __syncthreads();

  // ---- projection MFMA: out[l][j], wave handles 32 l x 64 j ----
  const f32x4 fz = {0.f, 0.f, 0.f, 0.f};
  f32x4 kacc[2][4], vacc[2][4];
#pragma unroll
  for (int i = 0; i < 2; i++)
#pragma unroll
    for (int jt = 0; jt < 4; jt++) { kacc[i][jt] = fz; vacc[i][jt] = fz; }

#pragma unroll
  for (int kc = 0; kc < 2; kc++) {
    bfx8 a0 = ldfrag(&hA[(wv * 32 + mm) * 72 + kc * 32 + qd * 8]);
    bfx8 a1 = ldfrag(&hA[(wv * 32 + 16 + mm) * 72 + kc * 32 + qd * 8]);
#pragma unroll
    for (int jt = 0; jt < 4; jt++) {
      bfx8 bkf = ldfrag(&WkB[(jt * 16 + mm) * 72 + kc * 32 + qd * 8]);
      bfx8 bvf = ldfrag(&WvB[(jt * 16 + mm) * 72 + kc * 32 + qd * 8]);
      kacc[0][jt] = MFMA16(a0, bkf, kacc[0][jt]);
      kacc[1][jt] = MFMA16(a1, bkf, kacc[1][jt]);
      vacc[0][jt] = MFMA16(a0, bvf, vacc[0][jt]);
      vacc[1][jt] = MFMA16(a1, bvf, vacc[1][jt]);
    }
  }

  // ---- postfix: K = rs*(raw - mu*Sk) + Tk -> phi;  V likewise (no phi) ----
#pragma unroll
  for (int lt2 = 0; lt2 < 2; lt2++) {
    float4 mu4 = *(const float4*)&mun[wv * 32 + lt2 * 16 + qd * 4];
    float4 rs4 = *(const float4*)&rsn[wv * 32 + lt2 * 16 + qd * 4];
    float muv[4] = {mu4.x, mu4.y, mu4.z, mu4.w};
    float rsv[4] = {rs4.x, rs4.y, rs4.z, rs4.w};
#pragma unroll
    for (int jt = 0; jt < 4; jt++) {
      int j = jt * 16 + mm;
      float Sk = SkT[j], Tk = SkT[64 + j], Sv = SkT[128 + j], Tv = SkT[192 + j];
#pragma unroll
      for (int r = 0; r < 4; r++) {
        float kk = rsv[r] * (kacc[lt2][jt][r] - muv[r] * Sk) + Tk;
        kacc[lt2][jt][r] = (kk > 0.f) ? (kk + 1.f) : __expf(kk);
        vacc[lt2][jt][r] = rsv[r] * (vacc[lt2][jt][r] - muv[r] * Sv) + Tv;
      }
    }
  }
  __syncthreads();   // hA/WkB/WvB dead -> overlay with pK/pV

  // ---- pack phi(K), V into [64 j][136 l] bf16 ----
#pragma unroll
  for (int lt2 = 0; lt2 < 2; lt2++) {
    int l0 = wv * 32 + lt2 * 16 + qd * 4;
#pragma unroll
    for (int jt = 0; jt < 4; jt++) {
      int j = jt * 16 + mm;
      uint2 dk, dv;
      dk.x = packbf2(kacc[lt2][jt][0], kacc[lt2][jt][1]);
      dk.y = packbf2(kacc[lt2][jt][2], kacc[lt2][jt][3]);
      dv.x = packbf2(vacc[lt2][jt][0], vacc[lt2][jt][1]);
      dv.y = packbf2(vacc[lt2][jt][2], vacc[lt2][jt][3]);
      *(uint2*)&pK[j * 136 + l0] = dk;
      *(uint2*)&pV[j * 136 + l0] = dv;
    }
  }
  __syncthreads();

  // ---- KV reduction MFMA: wave = head pair {2wv, 2wv+1}; A=phi(K)^T, B=V ----
  {
    f32x4 racc = fz;
#pragma unroll
    for (int kb = 0; kb < 4; kb++) {
      bfx8 ak = ldfrag(&pK[(wv * 16 + mm) * 136 + kb * 32 + qd * 8]);
      bfx8 bv8 = ldfrag(&pV[(wv * 16 + mm) * 136 + kb * 32 + qd * 8]);
      racc = MFMA16(ak, bv8, racc);
    }
    int eh = mm >> 3, e = mm & 7;
#pragma unroll
    for (int r = 0; r < 4; r++) {
      int row = qd * 4 + r;
      if ((row >> 3) == eh)
        atomicAdd(&wKV[(b * NH + wv * 2 + eh) * 64 + (row & 7) * 8 + e], racc[r]);
    }
  }
  // ---- Z: row sums of pK ----
  if (tid < 64) {
    const unsigned* kr = (const unsigned*)&pK[tid * 136];
    float zs = 0.f;
#pragma unroll
    for (int i = 0; i < 64; i++) { unsigned d = kr[i]; zs += bflo(d) + bfhi(d); }
    atomicAdd(&wZ[b * 64 + tid], zs);
  }
}

// ---------------- K3: Q MFMA + readout + O MFMA + residual -> yT tiled bf16 ----------------
// 256 threads, 128 l, grid NB*64.  LDS 41728 B -> 3 blocks/CU.
__global__ __launch_bounds__(256, 3) void k_qy(
    const unsigned short* __restrict__ xnb,
    const float* __restrict__ lnw, const float* __restrict__ lnb,
    const float* __restrict__ Wq, const float* __restrict__ bq,
    const float* __restrict__ Wo, const float* __restrict__ bo,
    const float* __restrict__ wmun, const float* __restrict__ wrsn,
    const float* __restrict__ wKV, const float* __restrict__ wZ,
    unsigned short* __restrict__ ytb) {
  __shared__ __align__(16) char smem[41728];
  unsigned short* hA  = (unsigned short*)smem;             // [128][72] xn bf16 -> overlaid by att
  unsigned short* qaA = (unsigned short*)smem;             // [128 l][72] phi(Q)/att
  unsigned short* WqB = (unsigned short*)(smem + 18432);   // [64 j][72 f] folded
  unsigned short* WoB = (unsigned short*)(smem + 27648);   // [64 f][72 e]
  float* kvz   = (float*)(smem + 36864);  // [576]
  float* mun   = (float*)(smem + 39168);  // [128]
  float* rsn   = (float*)(smem + 39680);  // [128]
  float* SqTq  = (float*)(smem + 40192);  // [128]
  float* Tpart = (float*)(smem + 40704);  // [4][64]

  const int tid = threadIdx.x;
  const int b = blockIdx.x >> 6;
  const int tI = blockIdx.x & 63;
  const int L0 = tI * 128;
  const int lane = tid & 63, wv = tid >> 6;
  const int mm = lane & 15, qd = lane >> 4;
  const unsigned short* xtile = xnb + (size_t)(b * 64 + tI) * 128 * 64;

  // ---- phase 0: stage Wq (folded) + Wo rows + kvz + xn tile + mu/rs ----
  {
    int jj = tid >> 2, g = tid & 3;
    int f0 = g * 16;
    float tqp = 0.f;
#pragma unroll
    for (int i = 0; i < 4; i++) {
      int f = f0 + i * 4;
      float4 wq4 = *(const float4*)&Wq[jj * NF + f];
      float4 wo4 = *(const float4*)&Wo[jj * NF + f];
      float4 lw  = *(const float4*)&lnw[f];
      float4 lb  = *(const float4*)&lnb[f];
      uint2 pq2, po2;
      pq2.x = packbf2(wq4.x * lw.x, wq4.y * lw.y);
      pq2.y = packbf2(wq4.z * lw.z, wq4.w * lw.w);
      po2.x = packbf2(wo4.x, wo4.y);
      po2.y = packbf2(wo4.z, wo4.w);
      *(uint2*)&WqB[jj * 72 + f] = pq2;
      *(uint2*)&WoB[jj * 72 + f] = po2;
      tqp += lb.x * wq4.x + lb.y * wq4.y + lb.z * wq4.z + lb.w * wq4.w;
    }
    Tpart[g * 64 + jj] = tqp;
  }
  for (int i = tid; i < 576; i += 256)
    kvz[i] = (i < 512) ? wKV[b * 512 + i] : wZ[b * 64 + i - 512];
  {
    int row = tid >> 1, half = tid & 1;
    const uint4* s4 = (const uint4*)(xtile + (size_t)row * 64 + half * 32);
    uint4 u0 = s4[0], u1 = s4[1], u2 = s4[2], u3 = s4[3];
    uint4* d4 = (uint4*)&hA[row * 72 + half * 32];
    d4[0] = u0; d4[1] = u1; d4[2] = u2; d4[3] = u3;
  }
  if (tid < 128) {
    mun[tid] = wmun[(size_t)b * NL + L0 + tid];
    rsn[tid] = wrsn[(size_t)b * NL + L0 + tid];
  }
  __syncthreads();

  if (tid < 64) {
    const unsigned* wr = (const unsigned*)(WqB + tid * 72);
    float s = 0.f;
#pragma unroll
    for (int i = 0; i < 32; i++) { unsigned d = wr[i]; s += bflo(d) + bfhi(d); }
    float t = Tpart[tid] + Tpart[64 + tid] + Tpart[128 + tid] + Tpart[192 + tid] + bq[tid];
    SqTq[tid] = s; SqTq[64 + tid] = t;
  }
  __syncthreads();

  const f32x4 fz = {0.f, 0.f, 0.f, 0.f};

  // ---- Q-MFMA; postfix+phi scatters into qaA (overlay of hA, own l-rows only) ----
  {
    f32x4 qacc[2][4];
#pragma unroll
    for (int i = 0; i < 2; i++)
#pragma unroll
      for (int jt = 0; jt < 4; jt++) qacc[i][jt] = fz;
#pragma unroll
    for (int kc = 0; kc < 2; kc++) {
      bfx8 a0 = ldfrag(&hA[(wv * 32 + mm) * 72 + kc * 32 + qd * 8]);
      bfx8 a1 = ldfrag(&hA[(wv * 32 + 16 + mm) * 72 + kc * 32 + qd * 8]);
#pragma unroll
      for (int jt = 0; jt < 4; jt++) {
        bfx8 bqf = ldfrag(&WqB[(jt * 16 + mm) * 72 + kc * 32 + qd * 8]);
        qacc[0][jt] = MFMA16(a0, bqf, qacc[0][jt]);
        qacc[1][jt] = MFMA16(a1, bqf, qacc[1][jt]);
      }
    }
#pragma unroll
    for (int lt2 = 0; lt2 < 2; lt2++) {
      float4 mu4 = *(const float4*)&mun[wv * 32 + lt2 * 16 + qd * 4];
      float4 rs4 = *(const float4*)&rsn[wv * 32 + lt2 * 16 + qd * 4];
      float muv[4] = {mu4.x, mu4.y, mu4.z, mu4.w};
      float rsv[4] = {rs4.x, rs4.y, rs4.z, rs4.w};
      int l0 = wv * 32 + lt2 * 16 + qd * 4;
#pragma unroll
      for (int jt = 0; jt < 4; jt++) {
        int j = jt * 16 + mm;
        float Sj = SqTq[j], Tj = SqTq[64 + j];
#pragma unroll
        for (int r = 0; r < 4; r++) {
          float q = rsv[r] * (qacc[lt2][jt][r] - muv[r] * Sj) + Tj;
          q = (q > 0.f) ? (q + 1.f) : __expf(q);
          qaA[(l0 + r) * 72 + j] = f2bf(q);
        }
      }
    }
  }
  __syncthreads();

  // ---- readout in place: thread = (4 l, 1 head) tile of qaA ----
  {
    int lt = tid & 31, hd = tid >> 5;
    int lbase = lt * 4;
    float qv[4][8];
#pragma unroll
    for (int i = 0; i < 4; i++) {
      uint4 u = *(const uint4*)&qaA[(lbase + i) * 72 + hd * 8];
      qv[i][0] = bflo(u.x); qv[i][1] = bfhi(u.x);
      qv[i][2] = bflo(u.y); qv[i][3] = bfhi(u.y);
      qv[i][4] = bflo(u.z); qv[i][5] = bfhi(u.z);
      qv[i][6] = bflo(u.w); qv[i][7] = bfhi(u.w);
    }
    float att[4][8], nrm[4];
#pragma unroll
    for (int i = 0; i < 4; i++) {
      nrm[i] = 1e-6f;
#pragma unroll
      for (int e = 0; e < 8; e++) att[i][e] = 0.f;
    }
#pragma unroll
    for (int d = 0; d < 8; d++) {
      float zd = kvz[512 + hd * 8 + d];
      float4 kva = *(const float4*)&kvz[hd * 64 + d * 8];
      float4 kvb = *(const float4*)&kvz[hd * 64 + d * 8 + 4];
#pragma unroll
      for (int i = 0; i < 4; i++) {
        float qq = qv[i][d];
        nrm[i] = fmaf(qq, zd, nrm[i]);
        att[i][0] = fmaf(qq, kva.x, att[i][0]);
        att[i][1] = fmaf(qq, kva.y, att[i][1]);
        att[i][2] = fmaf(qq, kva.z, att[i][2]);
        att[i][3] = fmaf(qq, kva.w, att[i][3]);
        att[i][4] = fmaf(qq, kvb.x, att[i][4]);
        att[i][5] = fmaf(qq, kvb.y, att[i][5]);
        att[i][6] = fmaf(qq, kvb.z, att[i][6]);
        att[i][7] = fmaf(qq, kvb.w, att[i][7]);
      }
    }
#pragma unroll
    for (int i = 0; i < 4; i++) {
      float inv = 1.f / nrm[i];
      uint4 o;
      o.x = packbf2(att[i][0] * inv, att[i][1] * inv);
      o.y = packbf2(att[i][2] * inv, att[i][3] * inv);
      o.z = packbf2(att[i][4] * inv, att[i][5] * inv);
      o.w = packbf2(att[i][6] * inv, att[i][7] * inv);
      *(uint4*)&qaA[(lbase + i) * 72 + hd * 8] = o;
    }
  }
  __syncthreads();

  // ---- O-MFMA: y[l][f] = att[l][e] . Wo[f][e]; epilogue -> yt tiled ----
  {
    f32x4 yacc[2][4];
#pragma unroll
    for (int i = 0; i < 2; i++)
#pragma unroll
      for (int ft = 0; ft < 4; ft++) yacc[i][ft] = fz;
#pragma unroll
    for (int ec = 0; ec < 2; ec++) {
      bfx8 a0 = ldfrag(&qaA[(wv * 32 + mm) * 72 + ec * 32 + qd * 8]);
      bfx8 a1 = ldfrag(&qaA[(wv * 32 + 16 + mm) * 72 + ec * 32 + qd * 8]);
#pragma unroll
      for (int ft = 0; ft < 4; ft++) {
        bfx8 bof = ldfrag(&WoB[(ft * 16 + mm) * 72 + ec * 32 + qd * 8]);
        yacc[0][ft] = MFMA16(a0, bof, yacc[0][ft]);
        yacc[1][ft] = MFMA16(a1, bof, yacc[1][ft]);
      }
    }
    // epilogue: + xn residual (from global xnb, L1/L2-hot) + bo -> tiled bf16 store
#pragma unroll
    for (int lt2 = 0; lt2 < 2; lt2++) {
      int l0 = wv * 32 + lt2 * 16 + qd * 4;
#pragma unroll
      for (int ft = 0; ft < 4; ft++) {
        int ff = ft * 16 + mm;
        float bof = bo[ff];
        float v0 = yacc[lt2][ft][0] + bf1(xtile[(size_t)(l0 + 0) * 64 + ff]) + bof;
        float v1 = yacc[lt2][ft][1] + bf1(xtile[(size_t)(l0 + 1) * 64 + ff]) + bof;
        float v2 = yacc[lt2][ft][2] + bf1(xtile[(size_t)(l0 + 2) * 64 + ff]) + bof;
        float v3 = yacc[lt2][ft][3] + bf1(xtile[(size_t)(l0 + 3) * 64 + ff]) + bof;
        uint2 o2;
        o2.x = packbf2(v0, v1);
        o2.y = packbf2(v2, v3);
        // tiled layout [b][l/32][f 64][32]: lgrp = L0/32 + wv, lpos = lt2*16+qd*4
        size_t idx = (((size_t)b * (NL / 32) + (L0 >> 5) + wv) * 64 + ff) * 32 + lt2 * 16 + qd * 4;
        *(uint2*)&ytb[idx] = o2;
      }
    }
  }
}

// ---------------- K4: temporal GEMM via MFMA, tiled layouts, no LDS ----------------
// out2[b,p,f] += sum_l Wlin[p,l]*y[b,f,l]
// ytb: [b][l/32][64 f][32 l], wlb: [l/32][96 p][32 l] -> fully coalesced frags.
__global__ __launch_bounds__(256) void k_temporal(
    const unsigned short* __restrict__ ytb, const unsigned short* __restrict__ wlb,
    float* __restrict__ out2) {
  const int tid = threadIdx.x, lane = tid & 63, wvx = tid >> 6;
  const int mm = lane & 15, qd = lane >> 4;
  const int b = blockIdx.x / TSPLIT;
  const int kc = blockIdx.x % TSPLIT;
  const f32x4 fz = {0.f, 0.f, 0.f, 0.f};
  f32x4 acc[6];
#pragma unroll
  for (int pt = 0; pt < 6; pt++) acc[pt] = fz;

#pragma unroll 2
  for (int ks = 0; ks < 8; ks++) {
    int lg = kc * 8 + ks;
    bfx8 bfr = ldfrag(&ytb[(((size_t)b * (NL / 32) + lg) * 64 + wvx * 16 + mm) * 32 + qd * 8]);
#pragma unroll
    for (int pt = 0; pt < 6; pt++) {
      bfx8 afr = ldfrag(&wlb[((size_t)lg * NP + pt * 16 + mm) * 32 + qd * 8]);
      acc[pt] = MFMA16(afr, bfr, acc[pt]);
    }
  }
  const int ff = wvx * 16 + mm;
#pragma unroll
  for (int pt = 0; pt < 6; pt++) {
#pragma unroll
    for (int r = 0; r < 4; r++) {
      int p = pt * 16 + qd * 4 + r;
      atomicAdd(&out2[((size_t)(b * NP + p)) * NF + ff], acc[pt][r]);
    }
  }
}

// ---------------- K5: +blin, RevIN denorm, projector ----------------
__global__ __launch_bounds__(64) void k_final(
    const float* __restrict__ out2, const float* __restrict__ blin,
    const float* __restrict__ gamma, const float* __restrict__ beta,
    const float* __restrict__ wmean, const float* __restrict__ wstd,
    const float* __restrict__ Wp, const float* __restrict__ bp,
    float* __restrict__ out) {
  int b = blockIdx.x / NP;
  int p = blockIdx.x % NP;
  int f = threadIdx.x;
  float v = out2[((size_t)(b * NP + p)) * NF + f] + blin[p];
  v = (v - beta[f]) / gamma[f];
  v = v * wstd[b * NF + f] + wmean[b * NF + f];
  float s = v * Wp[f];
#pragma unroll
  for (int off = 32; off > 0; off >>= 1)
    s += __shfl_down(s, off, 64);
  if (f == 0) out[blockIdx.x] = s + bp[0];
}

extern "C" void kernel_launch(void* const* d_in, const int* in_sizes, int n_in,
                              void* d_out, int out_size, void* d_ws, size_t ws_size,
                              hipStream_t stream) {
  const float* x     = (const float*)d_in[0];
  const float* gamma = (const float*)d_in[1];
  const float* beta  = (const float*)d_in[2];
  const float* lnw   = (const float*)d_in[3];
  const float* lnb   = (const float*)d_in[4];
  const float* Wq    = (const float*)d_in[5];
  const float* bq    = (const float*)d_in[6];
  const float* Wk    = (const float*)d_in[7];
  const float* bk    = (const float*)d_in[8];
  const float* Wv    = (const float*)d_in[9];
  const float* bv    = (const float*)d_in[10];
  const float* Wo    = (const float*)d_in[11];
  const float* bo    = (const float*)d_in[12];
  const float* Wlin  = (const float*)d_in[13];
  const float* blin  = (const float*)d_in[14];
  const float* Wp    = (const float*)d_in[15];
  const float* bp    = (const float*)d_in[16];
  float* out = (float*)d_out;
  float* ws  = (float*)d_ws;

  float* wmean = ws + WS_MEAN;
  float* wstd  = ws + WS_STD;
  float* wrstd = ws + WS_RSTD;
  float* wKV   = ws + WS_KV;
  float* wZ    = ws + WS_Z;
  float* wout2 = ws + WS_OUT2;
  float* wmun  = ws + WS_MUN;
  float* wrsn  = ws + WS_RSN;
  unsigned short* wlb = (unsigned short*)(ws + WS_WLB);
  unsigned short* xnb = (unsigned short*)(ws + WS_XNB);
  unsigned short* ytb = (unsigned short*)(ws + WS_YT);

  (void)hipMemsetAsync(wKV, 0, (size_t)(16384 + 2048 + 196608) * sizeof(float), stream);

  k_stats<<<NB * NF, 256, 0, stream>>>(x, wmean, wstd, wrstd);
  k_wlb<<<NP * NL / 8 / 256, 256, 0, stream>>>(Wlin, wlb);
  k_kv<<<NB * 64, 256, 0, stream>>>(x, gamma, beta, lnw, lnb, Wk, bk, Wv, bv,
                                    wmean, wrstd, wKV, wZ, wmun, wrsn, xnb);
  k_qy<<<NB * 64, 256, 0, stream>>>(xnb, lnw, lnb, Wq, bq, Wo, bo,
                                    wmun, wrsn, wKV, wZ, ytb);
  k_temporal<<<NB * TSPLIT, 256, 0, stream>>>(ytb, wlb, wout2);
  k_final<<<NB * NP, 64, 0, stream>>>(wout2, blin, gamma, beta, wmean, wstd, Wp, bp, out);
}